// Round 1
// baseline (39640.671 us; speedup 1.0000x reference)
//
#include <hip/hip_runtime.h>
#include <hip/hip_bf16.h>

#define HWPX 65536           // H*W
#define CHN  256

// ---------------------------------------------------------------- MLP
__global__ void mlp_kernel(const float* __restrict__ pred_box,
                           const float* __restrict__ score,
                           const float* __restrict__ W1, const float* __restrict__ b1,
                           const float* __restrict__ W2, const float* __restrict__ b2,
                           const float* __restrict__ W3, const float* __restrict__ b3,
                           float* __restrict__ objf) {
  __shared__ float obj[25];
  __shared__ float h1[256];
  __shared__ float h2[256];
  const int box = blockIdx.x;          // 0..127  (b*32+n)
  const int tid = threadIdx.x;         // 0..255
  if (tid < 24) obj[tid] = pred_box[box * 24 + tid];
  if (tid == 24) obj[24] = score[box];
  __syncthreads();
  float acc = b1[tid];
  #pragma unroll
  for (int k = 0; k < 25; ++k) acc = fmaf(obj[k], W1[k * 256 + tid], acc);
  h1[tid] = fmaxf(acc, 0.f);
  __syncthreads();
  acc = b2[tid];
  #pragma unroll 8
  for (int k = 0; k < 256; ++k) acc = fmaf(h1[k], W2[k * 256 + tid], acc);
  h2[tid] = fmaxf(acc, 0.f);
  __syncthreads();
  acc = b3[tid];
  #pragma unroll 8
  for (int k = 0; k < 256; ++k) acc = fmaf(h2[k], W3[k * 256 + tid], acc);
  objf[box * 256 + tid] = acc * score[box];
}

// ---------------------------------------------------------------- box bounds
__global__ void bounds_kernel(const float* __restrict__ pred_box,
                              int* __restrict__ bnds) {
  const int t = threadIdx.x;           // 0..127
  const float* p = pred_box + t * 24;
  float gx0 = 1e30f, gx1 = -1e30f, gy0 = 1e30f, gy1 = -1e30f;
  #pragma unroll
  for (int j = 0; j < 8; ++j) {
    float gx = floorf((p[j * 3 + 0] + 51.2f) / 0.4f);
    float gy = floorf((p[j * 3 + 1] + 51.2f) / 0.4f);
    gx0 = fminf(gx0, gx); gx1 = fmaxf(gx1, gx);
    gy0 = fminf(gy0, gy); gy1 = fmaxf(gy1, gy);
  }
  bnds[t * 4 + 0] = (int)fminf(fmaxf(gx0, 0.f), 255.f);
  bnds[t * 4 + 1] = (int)fminf(fmaxf(gx1, 0.f), 255.f);
  bnds[t * 4 + 2] = (int)fminf(fmaxf(gy0, 0.f), 255.f);
  bnds[t * 4 + 3] = (int)fminf(fmaxf(gy1, 0.f), 255.f);
}

// ---------------------------------------------------------------- rasterize + gather -> NCHW
__global__ void raster_kernel(const int* __restrict__ bnds,
                              const float* __restrict__ objf,
                              float* __restrict__ out) {
  const int y = blockIdx.x;
  const int b = blockIdx.y;
  const int x = threadIdx.x;
  __shared__ int sb[128];
  if (x < 128) sb[x] = bnds[b * 128 + x];
  __syncthreads();
  int last = -1;
  #pragma unroll
  for (int n = 0; n < 32; ++n) {
    int bx0 = sb[n * 4 + 0], bx1 = sb[n * 4 + 1];
    int by0 = sb[n * 4 + 2], by1 = sb[n * 4 + 3];
    if (x >= bx0 && x <= bx1 && y >= by0 && y <= by1) last = n;
  }
  const float* f = objf + (b * 32 + (last < 0 ? 0 : last)) * 256;
  float* o = out + (size_t)b * 256 * HWPX + y * 256 + x;
  if (last >= 0) {
    for (int c = 0; c < 256; ++c) o[(size_t)c * HWPX] = f[c];
  } else {
    for (int c = 0; c < 256; ++c) o[(size_t)c * HWPX] = 0.f;
  }
}

// ---------------------------------------------------------------- conv 3x3 SAME, one batch
// grid: (16 co-groups, 64 tiles), block 256.
// tile: 64x16 px, 16 co; each thread: 4 consecutive x, 16 co.
__global__ __launch_bounds__(256) void conv_kernel(const float* __restrict__ in,
                                                   const float* __restrict__ w,
                                                   float* __restrict__ out) {
  __shared__ float sIn[4][18][68];   // 4 ci, 16+2 rows, 64+2 (+pad to 68 for b128 align)
  __shared__ float sW[4][9][16];     // ci, kykx, co
  const int co0 = blockIdx.x * 16;
  const int t   = blockIdx.y;
  const int x0  = (t & 3) * 64;
  const int y0  = (t >> 2) * 16;
  const int tid = threadIdx.x;
  const int xl  = (tid & 15) * 4;
  const int yl  = tid >> 4;

  float4 acc[16];
  #pragma unroll
  for (int co = 0; co < 16; ++co) acc[co] = make_float4(0.f, 0.f, 0.f, 0.f);

  for (int cc = 0; cc < 64; ++cc) {
    const int ci0 = cc * 4;
    __syncthreads();
    // stage input 4 x 18 x 66 (zero-padded halo)
    for (int idx = tid; idx < 4752; idx += 256) {
      int ci = idx / 1188;
      int r  = idx - ci * 1188;
      int yy = r / 66;
      int xx = r - yy * 66;
      int gy = y0 + yy - 1;
      int gx = x0 + xx - 1;
      float v = 0.f;
      if (gy >= 0 && gy < 256 && gx >= 0 && gx < 256)
        v = in[(size_t)(ci0 + ci) * HWPX + gy * 256 + gx];
      sIn[ci][yy][xx] = v;
    }
    // stage weights 16co x 4ci x 9
    for (int idx = tid; idx < 576; idx += 256) {
      int co = idx / 36;
      int r  = idx - co * 36;
      int ci = r / 9;
      int k  = r - ci * 9;
      sW[ci][k][co] = w[(size_t)(co0 + co) * 2304 + (ci0 + ci) * 9 + k];
    }
    __syncthreads();
    #pragma unroll
    for (int ci = 0; ci < 4; ++ci) {
      #pragma unroll
      for (int ky = 0; ky < 3; ++ky) {
        const float* row = &sIn[ci][yl + ky][xl];
        float4 a4 = *(const float4*)row;
        float a5 = row[4], a6 = row[5];
        float inv[6] = {a4.x, a4.y, a4.z, a4.w, a5, a6};
        #pragma unroll
        for (int kx = 0; kx < 3; ++kx) {
          const float4* wp = (const float4*)&sW[ci][ky * 3 + kx][0];
          float4 w0 = wp[0], w1 = wp[1], w2 = wp[2], w3 = wp[3];
          const float wv[16] = {w0.x, w0.y, w0.z, w0.w, w1.x, w1.y, w1.z, w1.w,
                                w2.x, w2.y, w2.z, w2.w, w3.x, w3.y, w3.z, w3.w};
          #pragma unroll
          for (int co = 0; co < 16; ++co) {
            acc[co].x = fmaf(inv[kx + 0], wv[co], acc[co].x);
            acc[co].y = fmaf(inv[kx + 1], wv[co], acc[co].y);
            acc[co].z = fmaf(inv[kx + 2], wv[co], acc[co].z);
            acc[co].w = fmaf(inv[kx + 3], wv[co], acc[co].w);
          }
        }
      }
    }
  }
  #pragma unroll
  for (int co = 0; co < 16; ++co) {
    float* o = out + (size_t)(co0 + co) * HWPX + (y0 + yl) * 256 + (x0 + xl);
    *(float4*)o = acc[co];
  }
}

// ---------------------------------------------------------------- BN stats, one batch (grid=256 channels)
__global__ void stats_kernel(const float* __restrict__ T,
                             const float* __restrict__ g,
                             const float* __restrict__ be,
                             float* __restrict__ sc, float* __restrict__ sh) {
  const int c = blockIdx.x;
  const float* p = T + (size_t)c * HWPX;
  double s = 0.0, s2 = 0.0;
  for (int i = threadIdx.x; i < HWPX; i += 256) {
    float v = p[i];
    s += (double)v;
    s2 += (double)v * (double)v;
  }
  #pragma unroll
  for (int off = 32; off > 0; off >>= 1) {
    s  += __shfl_down(s, off);
    s2 += __shfl_down(s2, off);
  }
  __shared__ double ls[4], ls2[4];
  const int wv = threadIdx.x >> 6;
  if ((threadIdx.x & 63) == 0) { ls[wv] = s; ls2[wv] = s2; }
  __syncthreads();
  if (threadIdx.x == 0) {
    double S  = ls[0] + ls[1] + ls[2] + ls[3];
    double S2 = ls2[0] + ls2[1] + ls2[2] + ls2[3];
    double m   = S / 65536.0;
    double var = S2 / 65536.0 - m * m;
    double inv = 1.0 / sqrt(var + 1e-5);
    float scv = (float)inv * g[c];
    sc[c] = scv;
    sh[c] = be[c] - (float)m * scv;
  }
}

// ---------------------------------------------------------------- BN apply + relu (in place), one batch
__global__ void bnrelu_kernel(float* __restrict__ T,
                              const float* __restrict__ sc,
                              const float* __restrict__ sh) {
  const size_t i = (size_t)blockIdx.x * 256 + threadIdx.x;  // float4 index
  const int c = (int)(i >> 14);
  float4 v = ((float4*)T)[i];
  const float s = sc[c], h = sh[c];
  v.x = fmaxf(fmaf(v.x, s, h), 0.f);
  v.y = fmaxf(fmaf(v.y, s, h), 0.f);
  v.z = fmaxf(fmaf(v.z, s, h), 0.f);
  v.w = fmaxf(fmaf(v.w, s, h), 0.f);
  ((float4*)T)[i] = v;
}

// ---------------------------------------------------------------- BN apply + residual + relu -> A (in place)
__global__ void bnres_kernel(const float* __restrict__ T,
                             const float* __restrict__ sc,
                             const float* __restrict__ sh,
                             float* __restrict__ A) {
  const size_t i = (size_t)blockIdx.x * 256 + threadIdx.x;
  const int c = (int)(i >> 14);
  float4 v = ((const float4*)T)[i];
  float4 a = ((float4*)A)[i];
  const float s = sc[c], h = sh[c];
  a.x = fmaxf(fmaf(v.x, s, h) + a.x, 0.f);
  a.y = fmaxf(fmaf(v.y, s, h) + a.y, 0.f);
  a.z = fmaxf(fmaf(v.z, s, h) + a.z, 0.f);
  a.w = fmaxf(fmaf(v.w, s, h) + a.w, 0.f);
  ((float4*)A)[i] = a;
}

// ----------------------------------------------------------------
extern "C" void kernel_launch(void* const* d_in, const int* in_sizes, int n_in,
                              void* d_out, int out_size, void* d_ws, size_t ws_size,
                              hipStream_t stream) {
  const float* pred_box   = (const float*)d_in[0];
  const float* pred_score = (const float*)d_in[1];
  const float* W1 = (const float*)d_in[2];
  const float* b1 = (const float*)d_in[3];
  const float* W2 = (const float*)d_in[4];
  const float* b2 = (const float*)d_in[5];
  const float* W3 = (const float*)d_in[6];
  const float* b3 = (const float*)d_in[7];
  const float* conv_w = (const float*)d_in[8];
  const float* gamma  = (const float*)d_in[9];
  const float* beta   = (const float*)d_in[10];
  float* out = (float*)d_out;

  char* wsb = (char*)d_ws;
  float* objf = (float*)(wsb + 0);                 // 128*256*4   = 131072
  int*   bnds = (int*)(wsb + 131072);              // 128*4*4     = 2048
  float* sc   = (float*)(wsb + 135168);            // 256*4
  float* sh   = (float*)(wsb + 136192);            // 256*4
  float* T1   = (float*)(wsb + (1u << 20));                    // 64 MB
  float* T2   = (float*)(wsb + (1u << 20) + (67108864u));      // 64 MB

  const size_t CHW = (size_t)256 * HWPX;           // floats per batch

  mlp_kernel<<<128, 256, 0, stream>>>(pred_box, pred_score, W1, b1, W2, b2, W3, b3, objf);
  bounds_kernel<<<1, 128, 0, stream>>>(pred_box, bnds);
  raster_kernel<<<dim3(256, 4), 256, 0, stream>>>(bnds, objf, out);

  for (int k = 0; k < 3; ++k) {
    const float* wk0 = conv_w + (size_t)(k * 2 + 0) * 589824;
    const float* wk1 = conv_w + (size_t)(k * 2 + 1) * 589824;
    const float* g0  = gamma + (k * 2 + 0) * 256;
    const float* g1  = gamma + (k * 2 + 1) * 256;
    const float* be0 = beta  + (k * 2 + 0) * 256;
    const float* be1 = beta  + (k * 2 + 1) * 256;
    for (int b = 0; b < 4; ++b) {
      float* Ab = out + (size_t)b * CHW;
      conv_kernel<<<dim3(16, 64), 256, 0, stream>>>(Ab, wk0, T1);
      stats_kernel<<<256, 256, 0, stream>>>(T1, g0, be0, sc, sh);
      bnrelu_kernel<<<16384, 256, 0, stream>>>(T1, sc, sh);
      conv_kernel<<<dim3(16, 64), 256, 0, stream>>>(T1, wk1, T2);
      stats_kernel<<<256, 256, 0, stream>>>(T2, g1, be1, sc, sh);
      bnres_kernel<<<16384, 256, 0, stream>>>(T2, sc, sh, Ab);
    }
  }
}

// Round 2
// 7765.888 us; speedup vs baseline: 5.1045x; 5.1045x over previous
//
#include <hip/hip_runtime.h>
#include <hip/hip_bf16.h>

typedef short short8 __attribute__((ext_vector_type(8)));
typedef float f32x4 __attribute__((ext_vector_type(4)));

#define MFMA16 __builtin_amdgcn_mfma_f32_16x16x32_bf16
#define HWPX 65536

__device__ __forceinline__ unsigned short f2bf(float f) {
  unsigned u = __float_as_uint(f);
  u += 0x7FFF + ((u >> 16) & 1);
  return (unsigned short)(u >> 16);
}
__device__ __forceinline__ float bf2f(unsigned short b) {
  return __uint_as_float(((unsigned)b) << 16);
}

// ---------------------------------------------------------------- MLP (unchanged)
__global__ void mlp_kernel(const float* __restrict__ pred_box,
                           const float* __restrict__ score,
                           const float* __restrict__ W1, const float* __restrict__ b1,
                           const float* __restrict__ W2, const float* __restrict__ b2,
                           const float* __restrict__ W3, const float* __restrict__ b3,
                           float* __restrict__ objf) {
  __shared__ float obj[25];
  __shared__ float h1[256];
  __shared__ float h2[256];
  const int box = blockIdx.x;
  const int tid = threadIdx.x;
  if (tid < 24) obj[tid] = pred_box[box * 24 + tid];
  if (tid == 24) obj[24] = score[box];
  __syncthreads();
  float acc = b1[tid];
  #pragma unroll
  for (int k = 0; k < 25; ++k) acc = fmaf(obj[k], W1[k * 256 + tid], acc);
  h1[tid] = fmaxf(acc, 0.f);
  __syncthreads();
  acc = b2[tid];
  #pragma unroll 8
  for (int k = 0; k < 256; ++k) acc = fmaf(h1[k], W2[k * 256 + tid], acc);
  h2[tid] = fmaxf(acc, 0.f);
  __syncthreads();
  acc = b3[tid];
  #pragma unroll 8
  for (int k = 0; k < 256; ++k) acc = fmaf(h2[k], W3[k * 256 + tid], acc);
  objf[box * 256 + tid] = acc * score[box];
}

// ---------------------------------------------------------------- box bounds (unchanged)
__global__ void bounds_kernel(const float* __restrict__ pred_box,
                              int* __restrict__ bnds) {
  const int t = threadIdx.x;
  const float* p = pred_box + t * 24;
  float gx0 = 1e30f, gx1 = -1e30f, gy0 = 1e30f, gy1 = -1e30f;
  #pragma unroll
  for (int j = 0; j < 8; ++j) {
    float gx = floorf((p[j * 3 + 0] + 51.2f) / 0.4f);
    float gy = floorf((p[j * 3 + 1] + 51.2f) / 0.4f);
    gx0 = fminf(gx0, gx); gx1 = fmaxf(gx1, gx);
    gy0 = fminf(gy0, gy); gy1 = fmaxf(gy1, gy);
  }
  bnds[t * 4 + 0] = (int)fminf(fmaxf(gx0, 0.f), 255.f);
  bnds[t * 4 + 1] = (int)fminf(fmaxf(gx1, 0.f), 255.f);
  bnds[t * 4 + 2] = (int)fminf(fmaxf(gy0, 0.f), 255.f);
  bnds[t * 4 + 3] = (int)fminf(fmaxf(gy1, 0.f), 255.f);
}

// ---------------------------------------------------------------- weight transform -> wt[cv][tap][co][ci] bf16
__global__ void wt_kernel(const float* __restrict__ w, unsigned short* __restrict__ wt) {
  int i = blockIdx.x * 256 + threadIdx.x;          // 6*9*256*256
  int ci = i & 255;
  int co = (i >> 8) & 255;
  int t = i >> 16;                                 // cv*9+tap
  int cv = t / 9, tap = t - cv * 9;
  wt[i] = f2bf(w[(size_t)cv * 589824 + co * 2304 + ci * 9 + tap]);
}

// ---------------------------------------------------------------- raster -> NHWC bf16
__global__ void raster_nhwc(const int* __restrict__ bnds,
                            const float* __restrict__ objf,
                            unsigned short* __restrict__ xB) {
  const int y = blockIdx.x;
  const int b = blockIdx.y;
  const int x = threadIdx.x;
  __shared__ int sb[128];
  __shared__ int lastA[256];
  if (x < 128) sb[x] = bnds[b * 128 + x];
  __syncthreads();
  int last = -1;
  #pragma unroll
  for (int n = 0; n < 32; ++n) {
    int bx0 = sb[n * 4 + 0], bx1 = sb[n * 4 + 1];
    int by0 = sb[n * 4 + 2], by1 = sb[n * 4 + 3];
    if (x >= bx0 && x <= bx1 && y >= by0 && y <= by1) last = n;
  }
  lastA[x] = last;
  __syncthreads();
  unsigned short* row = xB + ((size_t)b * HWPX + y * 256) * 256;
  for (int it = 0; it < 32; ++it) {
    int s = x + 256 * it;
    int px = s >> 5;
    int c8 = (s & 31) * 8;
    int ln = lastA[px];
    short8 v = {0, 0, 0, 0, 0, 0, 0, 0};
    if (ln >= 0) {
      const float* f = objf + (b * 32 + ln) * 256 + c8;
      #pragma unroll
      for (int j = 0; j < 8; ++j) v[j] = (short)f2bf(f[j]);
    }
    *(short8*)(row + px * 256 + c8) = v;
  }
}

// ---------------------------------------------------------------- implicit-GEMM conv 3x3, bf16 MFMA
// grid (8, 256): bx -> xt=bx&3 (64px), ct=bx>>2 (128co); by = image row.
// block 256 = 4 waves (2M x 2N), wave tile 32px x 64co, acc[2][4].
__global__ __launch_bounds__(256) void conv_mfma(const unsigned short* __restrict__ in,
                                                 const unsigned short* __restrict__ wt,
                                                 float* __restrict__ outT) {
  __shared__ unsigned short lds[2][3 * 68 * 40];
  const int bx = blockIdx.x;
  const int y = blockIdx.y;
  const int x0 = (bx & 3) * 64;
  const int co_blk = (bx >> 2) * 128;
  const int tid = threadIdx.x;
  const int lane = tid & 63;
  const int wid = tid >> 6;
  const int wr = (wid >> 1) & 1;
  const int wc = wid & 1;
  const int i15 = lane & 15;
  const int khi = lane >> 4;
  const int k8 = khi * 8;

  f32x4 acc[2][4];
  #pragma unroll
  for (int a = 0; a < 2; ++a)
    #pragma unroll
    for (int b = 0; b < 4; ++b) acc[a][b] = (f32x4){0.f, 0.f, 0.f, 0.f};

  short8 st0, st1, st2, st3;

  auto issue = [&](int ci0) {
    #pragma unroll
    for (int i = 0; i < 3; ++i) {
      int idx = tid + 256 * i;
      int row = idx >> 8, rem = idx & 255, col = rem >> 2, g = rem & 3;
      int yg = y + row - 1;
      short8 v = {0, 0, 0, 0, 0, 0, 0, 0};
      if ((unsigned)yg < 256u)
        v = *(const short8*)(in + ((yg * 256 + x0 + col) * 256 + ci0 + g * 8));
      if (i == 0) st0 = v; else if (i == 1) st1 = v; else st2 = v;
    }
    short8 v = {0, 0, 0, 0, 0, 0, 0, 0};
    if (tid < 24) {
      int row = tid >> 3, h = (tid >> 2) & 1, g = tid & 3;
      int yg = y + row - 1;
      int xg = x0 + (h ? 64 : -1);
      if ((unsigned)yg < 256u && (unsigned)xg < 256u)
        v = *(const short8*)(in + ((yg * 256 + xg) * 256 + ci0 + g * 8));
    }
    st3 = v;
  };

  auto commit = [&](int buf) {
    #pragma unroll
    for (int i = 0; i < 3; ++i) {
      int idx = tid + 256 * i;
      int row = idx >> 8, rem = idx & 255, col = rem >> 2, g = rem & 3;
      *(short8*)&lds[buf][(row * 68 + col + 1) * 40 + g * 8] = (i == 0 ? st0 : i == 1 ? st1 : st2);
    }
    if (tid < 24) {
      int row = tid >> 3, h = (tid >> 2) & 1, g = tid & 3;
      *(short8*)&lds[buf][(row * 68 + (h ? 65 : 0)) * 40 + g * 8] = st3;
    }
  };

  auto compute = [&](int buf, int c) {
    const unsigned short* wp0 = wt + ((co_blk + wc * 64 + i15) * 256 + c * 32 + k8);
    const unsigned short* lb = &lds[buf][(wr * 32 + i15) * 40 + k8];
    #pragma unroll
    for (int ky = 0; ky < 3; ++ky) {
      #pragma unroll
      for (int kx = 0; kx < 3; ++kx) {
        const int tap = ky * 3 + kx;
        short8 a0 = *(const short8*)(lb + (ky * 68 + kx) * 40);
        short8 a1 = *(const short8*)(lb + (ky * 68 + kx + 16) * 40);
        const unsigned short* bp = wp0 + tap * 65536;
        short8 b0 = *(const short8*)(bp);
        short8 b1 = *(const short8*)(bp + 4096);
        short8 b2 = *(const short8*)(bp + 8192);
        short8 b3 = *(const short8*)(bp + 12288);
        acc[0][0] = MFMA16(a0, b0, acc[0][0], 0, 0, 0);
        acc[0][1] = MFMA16(a0, b1, acc[0][1], 0, 0, 0);
        acc[0][2] = MFMA16(a0, b2, acc[0][2], 0, 0, 0);
        acc[0][3] = MFMA16(a0, b3, acc[0][3], 0, 0, 0);
        acc[1][0] = MFMA16(a1, b0, acc[1][0], 0, 0, 0);
        acc[1][1] = MFMA16(a1, b1, acc[1][1], 0, 0, 0);
        acc[1][2] = MFMA16(a1, b2, acc[1][2], 0, 0, 0);
        acc[1][3] = MFMA16(a1, b3, acc[1][3], 0, 0, 0);
      }
    }
  };

  issue(0);
  commit(0);
  __syncthreads();
  for (int c = 0; c < 8; ++c) {
    const int cur = c & 1;
    if (c < 7) issue((c + 1) * 32);
    compute(cur, c);
    if (c < 7) commit(cur ^ 1);
    __syncthreads();
  }

  #pragma unroll
  for (int mf = 0; mf < 2; ++mf) {
    #pragma unroll
    for (int nf = 0; nf < 4; ++nf) {
      float* o = outT + (y * 256 + x0 + wr * 32 + mf * 16 + khi * 4) * 256
                 + co_blk + wc * 64 + nf * 16 + i15;
      #pragma unroll
      for (int r = 0; r < 4; ++r) o[r * 256] = acc[mf][nf][r];
    }
  }
}

// ---------------------------------------------------------------- BN stats pass 1: per-px-block partial sums
__global__ void stats1(const float* __restrict__ T, double* __restrict__ part) {
  const int p = blockIdx.x;          // 256 px-blocks of 256 px
  const int ch = threadIdx.x;
  const float* base = T + (size_t)p * 65536 + ch;
  double s = 0.0, s2 = 0.0;
  #pragma unroll 4
  for (int i = 0; i < 256; ++i) {
    double v = (double)base[i * 256];
    s += v; s2 += v * v;
  }
  part[(p * 256 + ch) * 2] = s;
  part[(p * 256 + ch) * 2 + 1] = s2;
}

// ---------------------------------------------------------------- BN stats pass 2 -> scale/shift
__global__ void stats2(const double* __restrict__ part,
                       const float* __restrict__ g, const float* __restrict__ be,
                       float* __restrict__ sc, float* __restrict__ sh) {
  const int ch = threadIdx.x;
  double s = 0.0, s2 = 0.0;
  for (int p = 0; p < 256; ++p) {
    s += part[(p * 256 + ch) * 2];
    s2 += part[(p * 256 + ch) * 2 + 1];
  }
  double m = s / 65536.0;
  double var = s2 / 65536.0 - m * m;
  double inv = 1.0 / sqrt(var + 1e-5);
  float scv = (float)inv * g[ch];
  sc[ch] = scv;
  sh[ch] = be[ch] - (float)m * scv;
}

// ---------------------------------------------------------------- BN+relu -> bf16 NHWC (conv2 input)
__global__ void bnrelu(const float* __restrict__ T,
                       const float* __restrict__ sc, const float* __restrict__ sh,
                       unsigned short* __restrict__ yB) {
  int i = blockIdx.x * 256 + threadIdx.x;      // float4 idx, 4,194,304
  float4 v = ((const float4*)T)[i];
  float4 s4 = ((const float4*)sc)[i & 63];
  float4 h4 = ((const float4*)sh)[i & 63];
  short4 o;
  o.x = (short)f2bf(fmaxf(fmaf(v.x, s4.x, h4.x), 0.f));
  o.y = (short)f2bf(fmaxf(fmaf(v.y, s4.y, h4.y), 0.f));
  o.z = (short)f2bf(fmaxf(fmaf(v.z, s4.z, h4.z), 0.f));
  o.w = (short)f2bf(fmaxf(fmaf(v.w, s4.w, h4.w), 0.f));
  ((short4*)yB)[i] = o;
}

// ---------------------------------------------------------------- BN + residual + relu; update xB (bf16); optionally write fp32 to T
__global__ void bnres(float* __restrict__ T,
                      const float* __restrict__ sc, const float* __restrict__ sh,
                      unsigned short* __restrict__ xB, int writeT) {
  int i = blockIdx.x * 256 + threadIdx.x;      // float4 idx
  float4 v = ((const float4*)T)[i];
  float4 s4 = ((const float4*)sc)[i & 63];
  float4 h4 = ((const float4*)sh)[i & 63];
  short4 rb = ((const short4*)xB)[i];
  float4 o;
  o.x = fmaxf(fmaf(v.x, s4.x, h4.x) + bf2f((unsigned short)rb.x), 0.f);
  o.y = fmaxf(fmaf(v.y, s4.y, h4.y) + bf2f((unsigned short)rb.y), 0.f);
  o.z = fmaxf(fmaf(v.z, s4.z, h4.z) + bf2f((unsigned short)rb.z), 0.f);
  o.w = fmaxf(fmaf(v.w, s4.w, h4.w) + bf2f((unsigned short)rb.w), 0.f);
  short4 ob;
  ob.x = (short)f2bf(o.x); ob.y = (short)f2bf(o.y);
  ob.z = (short)f2bf(o.z); ob.w = (short)f2bf(o.w);
  ((short4*)xB)[i] = ob;
  if (writeT) ((float4*)T)[i] = o;
}

// ---------------------------------------------------------------- NHWC fp32 -> NCHW fp32 (final output)
__global__ void transpose_k(const float* __restrict__ T, float* __restrict__ out) {
  __shared__ float tl[64][69];
  const int px0 = blockIdx.x * 64;
  const int ch0 = blockIdx.y * 64;
  const int tid = threadIdx.x;
  #pragma unroll
  for (int i = 0; i < 16; ++i) {
    int p = (tid >> 6) + 4 * i;
    int c = tid & 63;
    tl[p][c] = T[(px0 + p) * 256 + ch0 + c];
  }
  __syncthreads();
  #pragma unroll
  for (int i = 0; i < 16; ++i) {
    int p = tid & 63;
    int c = (tid >> 6) + 4 * i;
    out[(ch0 + c) * HWPX + px0 + p] = tl[p][c];
  }
}

// ----------------------------------------------------------------
extern "C" void kernel_launch(void* const* d_in, const int* in_sizes, int n_in,
                              void* d_out, int out_size, void* d_ws, size_t ws_size,
                              hipStream_t stream) {
  const float* pred_box   = (const float*)d_in[0];
  const float* pred_score = (const float*)d_in[1];
  const float* W1 = (const float*)d_in[2];
  const float* b1 = (const float*)d_in[3];
  const float* W2 = (const float*)d_in[4];
  const float* b2 = (const float*)d_in[5];
  const float* W3 = (const float*)d_in[6];
  const float* b3 = (const float*)d_in[7];
  const float* conv_w = (const float*)d_in[8];
  const float* gamma  = (const float*)d_in[9];
  const float* beta   = (const float*)d_in[10];
  float* out = (float*)d_out;

  char* wsb = (char*)d_ws;
  float* objf = (float*)(wsb + 0);
  int*   bnds = (int*)(wsb + 0x40000);
  float* sc   = (float*)(wsb + 0x42000);
  float* sh   = (float*)(wsb + 0x42400);
  double* part = (double*)(wsb + 0x100000);
  unsigned short* wtAll = (unsigned short*)(wsb + 0x200000);          // 6.75 MB
  unsigned short* xB    = (unsigned short*)(wsb + (size_t)16 * 1024 * 1024);   // 128 MB
  unsigned short* yB    = (unsigned short*)(wsb + (size_t)144 * 1024 * 1024);  // 32 MB
  float* T              = (float*)(wsb + (size_t)176 * 1024 * 1024);           // 64 MB

  const size_t CHW = (size_t)256 * HWPX;

  mlp_kernel<<<128, 256, 0, stream>>>(pred_box, pred_score, W1, b1, W2, b2, W3, b3, objf);
  bounds_kernel<<<1, 128, 0, stream>>>(pred_box, bnds);
  wt_kernel<<<13824, 256, 0, stream>>>(conv_w, wtAll);
  raster_nhwc<<<dim3(256, 4), 256, 0, stream>>>(bnds, objf, xB);

  for (int k = 0; k < 3; ++k) {
    for (int b = 0; b < 4; ++b) {
      unsigned short* xb = xB + (size_t)b * CHW;
      conv_mfma<<<dim3(8, 256), 256, 0, stream>>>(xb, wtAll + (size_t)(k * 2 + 0) * 589824, T);
      stats1<<<256, 256, 0, stream>>>(T, part);
      stats2<<<1, 256, 0, stream>>>(part, gamma + (k * 2 + 0) * 256, beta + (k * 2 + 0) * 256, sc, sh);
      bnrelu<<<16384, 256, 0, stream>>>(T, sc, sh, yB);
      conv_mfma<<<dim3(8, 256), 256, 0, stream>>>(yB, wtAll + (size_t)(k * 2 + 1) * 589824, T);
      stats1<<<256, 256, 0, stream>>>(T, part);
      stats2<<<1, 256, 0, stream>>>(part, gamma + (k * 2 + 1) * 256, beta + (k * 2 + 1) * 256, sc, sh);
      bnres<<<16384, 256, 0, stream>>>(T, sc, sh, xb, k == 2 ? 1 : 0);
      if (k == 2) transpose_k<<<dim3(1024, 4), 256, 0, stream>>>(T, out + (size_t)b * CHW);
    }
  }
}

// Round 3
// 4300.180 us; speedup vs baseline: 9.2184x; 1.8059x over previous
//
#include <hip/hip_runtime.h>
#include <hip/hip_bf16.h>

typedef short short8 __attribute__((ext_vector_type(8)));
typedef float f32x16 __attribute__((ext_vector_type(16)));

#define MFMA32 __builtin_amdgcn_mfma_f32_32x32x16_bf16
#define HWPX 65536

#define GLDS16(gp, lp) __builtin_amdgcn_global_load_lds( \
    (const __attribute__((address_space(1))) unsigned int*)(gp), \
    (__attribute__((address_space(3))) unsigned int*)(lp), 16, 0, 0)

__device__ __forceinline__ unsigned short f2bf(float f) {
  unsigned u = __float_as_uint(f);
  u += 0x7FFF + ((u >> 16) & 1);
  return (unsigned short)(u >> 16);
}
__device__ __forceinline__ float bf2f(unsigned short b) {
  return __uint_as_float(((unsigned)b) << 16);
}

// ---------------------------------------------------------------- MLP
__global__ void mlp_kernel(const float* __restrict__ pred_box,
                           const float* __restrict__ score,
                           const float* __restrict__ W1, const float* __restrict__ b1,
                           const float* __restrict__ W2, const float* __restrict__ b2,
                           const float* __restrict__ W3, const float* __restrict__ b3,
                           float* __restrict__ objf) {
  __shared__ float obj[25];
  __shared__ float h1[256];
  __shared__ float h2[256];
  const int box = blockIdx.x;
  const int tid = threadIdx.x;
  if (tid < 24) obj[tid] = pred_box[box * 24 + tid];
  if (tid == 24) obj[24] = score[box];
  __syncthreads();
  float acc = b1[tid];
  #pragma unroll
  for (int k = 0; k < 25; ++k) acc = fmaf(obj[k], W1[k * 256 + tid], acc);
  h1[tid] = fmaxf(acc, 0.f);
  __syncthreads();
  acc = b2[tid];
  #pragma unroll 8
  for (int k = 0; k < 256; ++k) acc = fmaf(h1[k], W2[k * 256 + tid], acc);
  h2[tid] = fmaxf(acc, 0.f);
  __syncthreads();
  acc = b3[tid];
  #pragma unroll 8
  for (int k = 0; k < 256; ++k) acc = fmaf(h2[k], W3[k * 256 + tid], acc);
  objf[box * 256 + tid] = acc * score[box];
}

// ---------------------------------------------------------------- box bounds
__global__ void bounds_kernel(const float* __restrict__ pred_box,
                              int* __restrict__ bnds) {
  const int t = threadIdx.x;
  const float* p = pred_box + t * 24;
  float gx0 = 1e30f, gx1 = -1e30f, gy0 = 1e30f, gy1 = -1e30f;
  #pragma unroll
  for (int j = 0; j < 8; ++j) {
    float gx = floorf((p[j * 3 + 0] + 51.2f) / 0.4f);
    float gy = floorf((p[j * 3 + 1] + 51.2f) / 0.4f);
    gx0 = fminf(gx0, gx); gx1 = fmaxf(gx1, gx);
    gy0 = fminf(gy0, gy); gy1 = fmaxf(gy1, gy);
  }
  bnds[t * 4 + 0] = (int)fminf(fmaxf(gx0, 0.f), 255.f);
  bnds[t * 4 + 1] = (int)fminf(fmaxf(gx1, 0.f), 255.f);
  bnds[t * 4 + 2] = (int)fminf(fmaxf(gy0, 0.f), 255.f);
  bnds[t * 4 + 3] = (int)fminf(fmaxf(gy1, 0.f), 255.f);
}

// ---------------------------------------------------------------- weight transform -> wt[cv][tap][co][ci] bf16
__global__ void wt_kernel(const float* __restrict__ w, unsigned short* __restrict__ wt) {
  int i = blockIdx.x * 256 + threadIdx.x;
  int ci = i & 255;
  int co = (i >> 8) & 255;
  int t = i >> 16;
  int cv = t / 9, tap = t - cv * 9;
  wt[i] = f2bf(w[(size_t)cv * 589824 + co * 2304 + ci * 9 + tap]);
}

// ---------------------------------------------------------------- raster -> NHWC bf16
__global__ void raster_nhwc(const int* __restrict__ bnds,
                            const float* __restrict__ objf,
                            unsigned short* __restrict__ xB) {
  const int y = blockIdx.x;
  const int b = blockIdx.y;
  const int x = threadIdx.x;
  __shared__ int sb[128];
  __shared__ int lastA[256];
  if (x < 128) sb[x] = bnds[b * 128 + x];
  __syncthreads();
  int last = -1;
  #pragma unroll
  for (int n = 0; n < 32; ++n) {
    int bx0 = sb[n * 4 + 0], bx1 = sb[n * 4 + 1];
    int by0 = sb[n * 4 + 2], by1 = sb[n * 4 + 3];
    if (x >= bx0 && x <= bx1 && y >= by0 && y <= by1) last = n;
  }
  lastA[x] = last;
  __syncthreads();
  unsigned short* row = xB + ((size_t)b * HWPX + y * 256) * 256;
  for (int it = 0; it < 32; ++it) {
    int s = x + 256 * it;
    int px = s >> 5;
    int c8 = (s & 31) * 8;
    int ln = lastA[px];
    short8 v = {0, 0, 0, 0, 0, 0, 0, 0};
    if (ln >= 0) {
      const float* f = objf + (b * 32 + ln) * 256 + c8;
      #pragma unroll
      for (int j = 0; j < 8; ++j) v[j] = (short)f2bf(f[j]);
    }
    *(short8*)(row + px * 256 + c8) = v;
  }
}

// ---------------------------------------------------------------- implicit-GEMM conv 3x3, bf16 MFMA 32x32x16
// 512 blocks (XCD-swizzled): tile = 2 rows x 64 px x 256 co.
// 4 waves: wr = px-row, wc = co-half. Wave: 64px x 128co, acc[2][4] f32x16.
// LDS: [4 rows][h(2)][ks(2)][66 cols][8 ci], col stride 16B, double-buffered.
__global__ __launch_bounds__(256, 2) void conv_mfma(const unsigned short* __restrict__ in,
                                                    const unsigned short* __restrict__ wt,
                                                    const unsigned short* __restrict__ zbuf,
                                                    float* __restrict__ T,
                                                    float* __restrict__ part) {
  __shared__ unsigned short lds[2][16 * 528];
  const int bid0 = blockIdx.x;
  const int bid = (bid0 & 7) * 64 + (bid0 >> 3);      // XCD swizzle (512 = 8*64, bijective)
  const int x0 = (bid & 3) * 64;
  const int y0 = (bid >> 2) * 2;
  const int tid = threadIdx.x;
  const int lane = tid & 63;
  const int wid = tid >> 6;
  const int wr = wid >> 1;
  const int wc = wid & 1;
  const int h = lane >> 5;
  const int l31 = lane & 31;
  const int col0 = l31 * 8;                            // shorts

  f32x16 acc[2][4];
  #pragma unroll
  for (int a = 0; a < 2; ++a)
    #pragma unroll
    for (int b = 0; b < 4; ++b)
      #pragma unroll
      for (int r = 0; r < 16; ++r) acc[a][b][r] = 0.f;

  const unsigned short* bbase = wt + ((size_t)(wc * 128 + l31)) * 256 + h * 8;

  short8 edgev;

  auto stage = [&](int c1, int buf) {
    const int ci0 = c1 * 32;
    #pragma unroll
    for (int i = 0; i < 4; ++i) {
      const int rowg = wid * 4 + i;                    // 16 slabs over 4 waves
      const int row = rowg >> 2;
      const int g = rowg & 3;
      const int yg = y0 + row - 1;
      unsigned short* lp = &lds[buf][((row << 2) | ((g & 1) << 1) | (g >> 1)) * 528 + 8];
      const unsigned short* gp;
      if ((unsigned)yg < 256u)
        gp = in + ((size_t)(yg * 256 + x0 + lane) * 256 + ci0 + g * 8);
      else
        gp = zbuf + lane * 8;
      GLDS16(gp, lp);
    }
  };

  auto edge_load = [&](int c1) {
    edgev = (short8){0, 0, 0, 0, 0, 0, 0, 0};
    if (tid < 32) {
      int row = tid >> 3, side = (tid >> 2) & 1, g = tid & 3;
      int yg = y0 + row - 1;
      int xg = x0 + (side ? 64 : -1);
      if ((unsigned)yg < 256u && (unsigned)xg < 256u)
        edgev = *(const short8*)(in + ((size_t)(yg * 256 + xg) * 256 + c1 * 32 + g * 8));
    }
  };
  auto edge_store = [&](int buf) {
    if (tid < 32) {
      int row = tid >> 3, side = (tid >> 2) & 1, g = tid & 3;
      *(short8*)&lds[buf][((row << 2) | ((g & 1) << 1) | (g >> 1)) * 528 + (side ? 65 : 0) * 8] = edgev;
    }
  };

  #define LOADA(s, d0, d1) { \
    const int ks_ = (s) / 9, tap_ = (s) % 9, ky_ = tap_ / 3, kx_ = tap_ % 3; \
    const unsigned short* p_ = lbase + ky_ * 2112 + ks_ * 528 + kx_ * 8 + col0; \
    d0 = *(const short8*)(p_); d1 = *(const short8*)(p_ + 256); }

  #define LOADB(s, d) { \
    const int ks_ = (s) / 9, tap_ = (s) % 9; \
    const unsigned short* p_ = bbase + (size_t)tap_ * 65536 + c * 32 + ks_ * 16; \
    d[0] = *(const short8*)(p_); d[1] = *(const short8*)(p_ + 8192); \
    d[2] = *(const short8*)(p_ + 16384); d[3] = *(const short8*)(p_ + 24576); }

  auto compute = [&](int buf, int c) {
    const unsigned short* lbase = &lds[buf][wr * 2112 + h * 1056];
    short8 Af[2][2];
    short8 Bf[3][4];
    LOADA(0, Af[0][0], Af[0][1]);
    LOADB(0, Bf[0]);
    LOADB(1, Bf[1]);
    #pragma unroll
    for (int s = 0; s < 18; ++s) {
      if (s + 2 < 18) LOADB(s + 2, Bf[(s + 2) % 3]);
      if (s + 1 < 18) LOADA(s + 1, Af[(s + 1) & 1][0], Af[(s + 1) & 1][1]);
      #pragma unroll
      for (int mf = 0; mf < 2; ++mf)
        #pragma unroll
        for (int nf = 0; nf < 4; ++nf)
          acc[mf][nf] = MFMA32(Af[s & 1][mf], Bf[s % 3][nf], acc[mf][nf], 0, 0, 0);
    }
  };

  stage(0, 0);
  edge_load(0);
  edge_store(0);
  __syncthreads();
  int cur = 0;
  for (int c = 0; c < 8; ++c) {
    if (c < 7) { stage(c + 1, cur ^ 1); edge_load(c + 1); }
    compute(cur, c);
    if (c < 7) edge_store(cur ^ 1);
    __syncthreads();
    cur ^= 1;
  }

  // epilogue: store fp32 NHWC + per-block BN partial sums
  #pragma unroll
  for (int mf = 0; mf < 2; ++mf)
    #pragma unroll
    for (int nf = 0; nf < 4; ++nf) {
      float* o = T + ((size_t)((y0 + wr) * 256) + x0 + mf * 32) * 256 + wc * 128 + nf * 32 + l31;
      #pragma unroll
      for (int r = 0; r < 16; ++r) {
        int m = (r & 3) + 8 * (r >> 2) + 4 * h;
        o[(size_t)m * 256] = acc[mf][nf][r];
      }
    }
  const int slot = bid * 2 + wr;
  #pragma unroll
  for (int nf = 0; nf < 4; ++nf) {
    float s = 0.f, s2 = 0.f;
    #pragma unroll
    for (int mf = 0; mf < 2; ++mf)
      #pragma unroll
      for (int r = 0; r < 16; ++r) {
        float v = acc[mf][nf][r];
        s += v; s2 += v * v;
      }
    s += __shfl_xor(s, 32);
    s2 += __shfl_xor(s2, 32);
    if (lane < 32) {
      part[((size_t)slot * 256 + wc * 128 + nf * 32 + lane) * 2] = s;
      part[((size_t)slot * 256 + wc * 128 + nf * 32 + lane) * 2 + 1] = s2;
    }
  }
  #undef LOADA
  #undef LOADB
}

// ---------------------------------------------------------------- BN stats reduce (grid = 256 channels)
__global__ void stats2(const float* __restrict__ part,
                       const float* __restrict__ g, const float* __restrict__ be,
                       float* __restrict__ sc, float* __restrict__ sh) {
  const int ch = blockIdx.x;
  const int t = threadIdx.x;
  double s = 0.0, s2 = 0.0;
  #pragma unroll
  for (int i = 0; i < 4; ++i) {
    int p = t + i * 256;
    s += (double)part[((size_t)p * 256 + ch) * 2];
    s2 += (double)part[((size_t)p * 256 + ch) * 2 + 1];
  }
  #pragma unroll
  for (int off = 32; off > 0; off >>= 1) {
    s += __shfl_down(s, off);
    s2 += __shfl_down(s2, off);
  }
  __shared__ double ls[4], ls2[4];
  if ((t & 63) == 0) { ls[t >> 6] = s; ls2[t >> 6] = s2; }
  __syncthreads();
  if (t == 0) {
    double S = ls[0] + ls[1] + ls[2] + ls[3];
    double S2 = ls2[0] + ls2[1] + ls2[2] + ls2[3];
    double m = S / 65536.0;
    double var = S2 / 65536.0 - m * m;
    double inv = 1.0 / sqrt(var + 1e-5);
    float scv = (float)inv * g[ch];
    sc[ch] = scv;
    sh[ch] = be[ch] - (float)m * scv;
  }
}

// ---------------------------------------------------------------- BN+relu -> bf16 NHWC
__global__ void bnrelu(const float* __restrict__ T,
                       const float* __restrict__ sc, const float* __restrict__ sh,
                       unsigned short* __restrict__ yB) {
  int i = blockIdx.x * 256 + threadIdx.x;
  float4 v = ((const float4*)T)[i];
  float4 s4 = ((const float4*)sc)[i & 63];
  float4 h4 = ((const float4*)sh)[i & 63];
  short4 o;
  o.x = (short)f2bf(fmaxf(fmaf(v.x, s4.x, h4.x), 0.f));
  o.y = (short)f2bf(fmaxf(fmaf(v.y, s4.y, h4.y), 0.f));
  o.z = (short)f2bf(fmaxf(fmaf(v.z, s4.z, h4.z), 0.f));
  o.w = (short)f2bf(fmaxf(fmaf(v.w, s4.w, h4.w), 0.f));
  ((short4*)yB)[i] = o;
}

// ---------------------------------------------------------------- BN + residual + relu
__global__ void bnres(float* __restrict__ T,
                      const float* __restrict__ sc, const float* __restrict__ sh,
                      unsigned short* __restrict__ xB, int writeT) {
  int i = blockIdx.x * 256 + threadIdx.x;
  float4 v = ((const float4*)T)[i];
  float4 s4 = ((const float4*)sc)[i & 63];
  float4 h4 = ((const float4*)sh)[i & 63];
  short4 rb = ((const short4*)xB)[i];
  float4 o;
  o.x = fmaxf(fmaf(v.x, s4.x, h4.x) + bf2f((unsigned short)rb.x), 0.f);
  o.y = fmaxf(fmaf(v.y, s4.y, h4.y) + bf2f((unsigned short)rb.y), 0.f);
  o.z = fmaxf(fmaf(v.z, s4.z, h4.z) + bf2f((unsigned short)rb.z), 0.f);
  o.w = fmaxf(fmaf(v.w, s4.w, h4.w) + bf2f((unsigned short)rb.w), 0.f);
  short4 ob;
  ob.x = (short)f2bf(o.x); ob.y = (short)f2bf(o.y);
  ob.z = (short)f2bf(o.z); ob.w = (short)f2bf(o.w);
  ((short4*)xB)[i] = ob;
  if (writeT) ((float4*)T)[i] = o;
}

// ---------------------------------------------------------------- NHWC fp32 -> NCHW fp32
__global__ void transpose_k(const float* __restrict__ T, float* __restrict__ out) {
  __shared__ float tl[64][69];
  const int px0 = blockIdx.x * 64;
  const int ch0 = blockIdx.y * 64;
  const int tid = threadIdx.x;
  #pragma unroll
  for (int i = 0; i < 16; ++i) {
    int p = (tid >> 6) + 4 * i;
    int c = tid & 63;
    tl[p][c] = T[(size_t)(px0 + p) * 256 + ch0 + c];
  }
  __syncthreads();
  #pragma unroll
  for (int i = 0; i < 16; ++i) {
    int p = tid & 63;
    int c = (tid >> 6) + 4 * i;
    out[(size_t)(ch0 + c) * HWPX + px0 + p] = tl[p][c];
  }
}

// ----------------------------------------------------------------
extern "C" void kernel_launch(void* const* d_in, const int* in_sizes, int n_in,
                              void* d_out, int out_size, void* d_ws, size_t ws_size,
                              hipStream_t stream) {
  const float* pred_box   = (const float*)d_in[0];
  const float* pred_score = (const float*)d_in[1];
  const float* W1 = (const float*)d_in[2];
  const float* b1 = (const float*)d_in[3];
  const float* W2 = (const float*)d_in[4];
  const float* b2 = (const float*)d_in[5];
  const float* W3 = (const float*)d_in[6];
  const float* b3 = (const float*)d_in[7];
  const float* conv_w = (const float*)d_in[8];
  const float* gamma  = (const float*)d_in[9];
  const float* beta   = (const float*)d_in[10];
  float* out = (float*)d_out;

  char* wsb = (char*)d_ws;
  float* objf = (float*)(wsb + 0);
  int*   bnds = (int*)(wsb + 0x40000);
  float* sc   = (float*)(wsb + 0x42000);
  float* sh   = (float*)(wsb + 0x42400);
  float* part = (float*)(wsb + 0x100000);                               // 2 MB
  unsigned short* zbuf = (unsigned short*)(wsb + 0x300000);             // 4 KB zeros
  unsigned short* wtAll = (unsigned short*)(wsb + 0x400000);            // 6.75 MB
  unsigned short* xB    = (unsigned short*)(wsb + (size_t)16 * 1024 * 1024);   // 128 MB
  unsigned short* yB    = (unsigned short*)(wsb + (size_t)144 * 1024 * 1024);  // 32 MB
  float* T              = (float*)(wsb + (size_t)176 * 1024 * 1024);           // 64 MB

  const size_t CHW = (size_t)256 * HWPX;

  hipMemsetAsync(zbuf, 0, 4096, stream);
  mlp_kernel<<<128, 256, 0, stream>>>(pred_box, pred_score, W1, b1, W2, b2, W3, b3, objf);
  bounds_kernel<<<1, 128, 0, stream>>>(pred_box, bnds);
  wt_kernel<<<13824, 256, 0, stream>>>(conv_w, wtAll);
  raster_nhwc<<<dim3(256, 4), 256, 0, stream>>>(bnds, objf, xB);

  for (int k = 0; k < 3; ++k) {
    for (int b = 0; b < 4; ++b) {
      unsigned short* xb = xB + (size_t)b * CHW;
      conv_mfma<<<512, 256, 0, stream>>>(xb, wtAll + (size_t)(k * 2 + 0) * 589824, zbuf, T, part);
      stats2<<<256, 256, 0, stream>>>(part, gamma + (k * 2 + 0) * 256, beta + (k * 2 + 0) * 256, sc, sh);
      bnrelu<<<16384, 256, 0, stream>>>(T, sc, sh, yB);
      conv_mfma<<<512, 256, 0, stream>>>(yB, wtAll + (size_t)(k * 2 + 1) * 589824, zbuf, T, part);
      stats2<<<256, 256, 0, stream>>>(part, gamma + (k * 2 + 1) * 256, beta + (k * 2 + 1) * 256, sc, sh);
      bnres<<<16384, 256, 0, stream>>>(T, sc, sh, xb, k == 2 ? 1 : 0);
      if (k == 2) transpose_k<<<dim3(1024, 4), 256, 0, stream>>>(T, out + (size_t)b * CHW);
    }
  }
}

// Round 4
// 2478.672 us; speedup vs baseline: 15.9927x; 1.7349x over previous
//
#include <hip/hip_runtime.h>
#include <hip/hip_bf16.h>

typedef short short8 __attribute__((ext_vector_type(8)));
typedef float f32x16 __attribute__((ext_vector_type(16)));

#define MFMA32 __builtin_amdgcn_mfma_f32_32x32x16_bf16
#define HWPX 65536

#define GLDS16(gp, lp) __builtin_amdgcn_global_load_lds( \
    (const __attribute__((address_space(1))) unsigned int*)(gp), \
    (__attribute__((address_space(3))) unsigned int*)(lp), 16, 0, 0)

__device__ __forceinline__ unsigned short f2bf(float f) {
  unsigned u = __float_as_uint(f);
  u += 0x7FFF + ((u >> 16) & 1);
  return (unsigned short)(u >> 16);
}
__device__ __forceinline__ float bf2f(unsigned short b) {
  return __uint_as_float(((unsigned)b) << 16);
}

// ---------------------------------------------------------------- MLP
__global__ void mlp_kernel(const float* __restrict__ pred_box,
                           const float* __restrict__ score,
                           const float* __restrict__ W1, const float* __restrict__ b1,
                           const float* __restrict__ W2, const float* __restrict__ b2,
                           const float* __restrict__ W3, const float* __restrict__ b3,
                           float* __restrict__ objf) {
  __shared__ float obj[25];
  __shared__ float h1[256];
  __shared__ float h2[256];
  const int box = blockIdx.x;
  const int tid = threadIdx.x;
  if (tid < 24) obj[tid] = pred_box[box * 24 + tid];
  if (tid == 24) obj[24] = score[box];
  __syncthreads();
  float acc = b1[tid];
  #pragma unroll
  for (int k = 0; k < 25; ++k) acc = fmaf(obj[k], W1[k * 256 + tid], acc);
  h1[tid] = fmaxf(acc, 0.f);
  __syncthreads();
  acc = b2[tid];
  #pragma unroll 8
  for (int k = 0; k < 256; ++k) acc = fmaf(h1[k], W2[k * 256 + tid], acc);
  h2[tid] = fmaxf(acc, 0.f);
  __syncthreads();
  acc = b3[tid];
  #pragma unroll 8
  for (int k = 0; k < 256; ++k) acc = fmaf(h2[k], W3[k * 256 + tid], acc);
  objf[box * 256 + tid] = acc * score[box];
}

// ---------------------------------------------------------------- box bounds
__global__ void bounds_kernel(const float* __restrict__ pred_box,
                              int* __restrict__ bnds) {
  const int t = threadIdx.x;
  const float* p = pred_box + t * 24;
  float gx0 = 1e30f, gx1 = -1e30f, gy0 = 1e30f, gy1 = -1e30f;
  #pragma unroll
  for (int j = 0; j < 8; ++j) {
    float gx = floorf((p[j * 3 + 0] + 51.2f) / 0.4f);
    float gy = floorf((p[j * 3 + 1] + 51.2f) / 0.4f);
    gx0 = fminf(gx0, gx); gx1 = fmaxf(gx1, gx);
    gy0 = fminf(gy0, gy); gy1 = fmaxf(gy1, gy);
  }
  bnds[t * 4 + 0] = (int)fminf(fmaxf(gx0, 0.f), 255.f);
  bnds[t * 4 + 1] = (int)fminf(fmaxf(gx1, 0.f), 255.f);
  bnds[t * 4 + 2] = (int)fminf(fmaxf(gy0, 0.f), 255.f);
  bnds[t * 4 + 3] = (int)fminf(fmaxf(gy1, 0.f), 255.f);
}

// ---------------------------------------------------------------- weight transform
// wt2 layout: [cv][tap][kslice(16)][coblk(8)][lane(64)][8ci] bf16 — each MFMA
// B-fragment (tap, 16-K slice, 32-co block) is one contiguous 1KB wave load.
// lane l: co = coblk*32 + (l&31), ci = kslice*16 + (l>>5)*8 + j.
__global__ void wt_kernel(const float* __restrict__ w, unsigned short* __restrict__ wt) {
  int i = blockIdx.x * 256 + threadIdx.x;          // 6*9*16*8*512 = 3,538,944
  int j = i & 7;
  int l = (i >> 3) & 63;
  int nb = (i >> 9) & 7;
  int ks = (i >> 12) & 15;
  int t2 = i >> 16;
  int tap = t2 % 9;
  int cv = t2 / 9;
  int co = nb * 32 + (l & 31);
  int ci = ks * 16 + ((l >> 5) << 3) + j;
  wt[i] = f2bf(w[(size_t)((cv * 256 + co) * 256 + ci) * 9 + tap]);
}

// ---------------------------------------------------------------- raster -> NHWC bf16
__global__ void raster_nhwc(const int* __restrict__ bnds,
                            const float* __restrict__ objf,
                            unsigned short* __restrict__ xB) {
  const int y = blockIdx.x;
  const int b = blockIdx.y;
  const int x = threadIdx.x;
  __shared__ int sb[128];
  __shared__ int lastA[256];
  if (x < 128) sb[x] = bnds[b * 128 + x];
  __syncthreads();
  int last = -1;
  #pragma unroll
  for (int n = 0; n < 32; ++n) {
    int bx0 = sb[n * 4 + 0], bx1 = sb[n * 4 + 1];
    int by0 = sb[n * 4 + 2], by1 = sb[n * 4 + 3];
    if (x >= bx0 && x <= bx1 && y >= by0 && y <= by1) last = n;
  }
  lastA[x] = last;
  __syncthreads();
  unsigned short* row = xB + ((size_t)b * HWPX + y * 256) * 256;
  for (int it = 0; it < 32; ++it) {
    int s = x + 256 * it;
    int px = s >> 5;
    int c8 = (s & 31) * 8;
    int ln = lastA[px];
    short8 v = {0, 0, 0, 0, 0, 0, 0, 0};
    if (ln >= 0) {
      const float* f = objf + (b * 32 + ln) * 256 + c8;
      #pragma unroll
      for (int j = 0; j < 8; ++j) v[j] = (short)f2bf(f[j]);
    }
    *(short8*)(row + px * 256 + c8) = v;
  }
}

// ---------------------------------------------------------------- implicit-GEMM conv 3x3, bf16 MFMA 32x32x16
// 512 blocks: tile = 2 rows x 64 px x 256 co. 4 waves = 4 co-quarters (64 co).
// Wave: 128 px x 64 co, acc[4][2] f32x16 (m-frag = (yr,xh), n-frag = co-32-block).
// B-frags are contiguous 1KB wave loads from wt2 (no L2 line waste).
__global__ __launch_bounds__(256, 2) void conv_mfma(const unsigned short* __restrict__ in,
                                                    const unsigned short* __restrict__ wt,
                                                    const unsigned short* __restrict__ zbuf,
                                                    float* __restrict__ T,
                                                    float* __restrict__ part) {
  __shared__ unsigned short lds[2][16 * 528];
  const int bid0 = blockIdx.x;
  const int bid = (bid0 & 7) * 64 + (bid0 >> 3);      // XCD swizzle (512 = 8*64, bijective)
  const int x0 = (bid & 3) * 64;
  const int y0 = (bid >> 2) * 2;
  const int tid = threadIdx.x;
  const int lane = tid & 63;
  const int wid = tid >> 6;                            // co-quarter
  const int h = lane >> 5;
  const int l31 = lane & 31;
  const int col0 = l31 * 8;

  f32x16 acc[4][2];
  #pragma unroll
  for (int a = 0; a < 4; ++a)
    #pragma unroll
    for (int b = 0; b < 2; ++b)
      #pragma unroll
      for (int r = 0; r < 16; ++r) acc[a][b][r] = 0.f;

  const unsigned short* wbase = wt + (size_t)(wid * 2) * 512 + lane * 8;

  short8 edgev;

  auto stage = [&](int c1, int buf) {
    const int ci0 = c1 * 32;
    #pragma unroll
    for (int i = 0; i < 4; ++i) {
      const int rowg = wid * 4 + i;                    // 16 slabs over 4 waves
      const int row = rowg >> 2;
      const int g = rowg & 3;
      const int yg = y0 + row - 1;
      unsigned short* lp = &lds[buf][((row << 2) | ((g & 1) << 1) | (g >> 1)) * 528 + 8];
      const unsigned short* gp;
      if ((unsigned)yg < 256u)
        gp = in + ((size_t)(yg * 256 + x0 + lane) * 256 + ci0 + g * 8);
      else
        gp = zbuf + lane * 8;
      GLDS16(gp, lp);
    }
  };

  auto edge_load = [&](int c1) {
    edgev = (short8){0, 0, 0, 0, 0, 0, 0, 0};
    if (tid < 32) {
      int row = tid >> 3, side = (tid >> 2) & 1, g = tid & 3;
      int yg = y0 + row - 1;
      int xg = x0 + (side ? 64 : -1);
      if ((unsigned)yg < 256u && (unsigned)xg < 256u)
        edgev = *(const short8*)(in + ((size_t)(yg * 256 + xg) * 256 + c1 * 32 + g * 8));
    }
  };
  auto edge_store = [&](int buf) {
    if (tid < 32) {
      int row = tid >> 3, side = (tid >> 2) & 1, g = tid & 3;
      *(short8*)&lds[buf][((row << 2) | ((g & 1) << 1) | (g >> 1)) * 528 + (side ? 65 : 0) * 8] = edgev;
    }
  };

  // A-frags: m = yr*2+xh. Row = yr+ky (stride 2112), K-unit = h*2+ks (stride 528),
  // x_lds = l31 + xh*32 + kx (stride 8).
  #define LOADA(s, d) { \
    const int ks_ = (s) / 9, tap_ = (s) % 9, ky_ = tap_ / 3, kx_ = tap_ % 3; \
    const unsigned short* p_ = lbase + ky_ * 2112 + ks_ * 528 + kx_ * 8 + col0; \
    d[0] = *(const short8*)(p_); \
    d[1] = *(const short8*)(p_ + 256); \
    d[2] = *(const short8*)(p_ + 2112); \
    d[3] = *(const short8*)(p_ + 2368); }

  #define LOADB(s, d) { \
    const unsigned short* p_ = wbase + (size_t)((((s) % 9) * 16 + c * 2 + (s) / 9) * 8) * 512; \
    d[0] = *(const short8*)(p_); d[1] = *(const short8*)(p_ + 512); }

  auto compute = [&](int buf, int c) {
    const unsigned short* lbase = &lds[buf][h * 1056];
    short8 Af[2][4];
    short8 Bf[3][2];
    LOADA(0, Af[0]);
    LOADB(0, Bf[0]);
    LOADB(1, Bf[1]);
    #pragma unroll
    for (int s = 0; s < 18; ++s) {
      if (s + 2 < 18) LOADB(s + 2, Bf[(s + 2) % 3]);
      if (s + 1 < 18) LOADA(s + 1, Af[(s + 1) & 1]);
      #pragma unroll
      for (int mf = 0; mf < 4; ++mf)
        #pragma unroll
        for (int nf = 0; nf < 2; ++nf)
          acc[mf][nf] = MFMA32(Af[s & 1][mf], Bf[s % 3][nf], acc[mf][nf], 0, 0, 0);
    }
  };

  stage(0, 0);
  edge_load(0);
  edge_store(0);
  __syncthreads();
  int cur = 0;
  for (int c = 0; c < 8; ++c) {
    if (c < 7) { stage(c + 1, cur ^ 1); edge_load(c + 1); }
    compute(cur, c);
    if (c < 7) edge_store(cur ^ 1);
    __syncthreads();
    cur ^= 1;
  }

  // epilogue: store fp32 NHWC + per-block BN partial sums
  #pragma unroll
  for (int mf = 0; mf < 4; ++mf)
    #pragma unroll
    for (int nf = 0; nf < 2; ++nf) {
      float* o = T + ((size_t)((y0 + (mf >> 1)) * 256) + x0 + (mf & 1) * 32) * 256
                 + wid * 64 + nf * 32 + l31;
      #pragma unroll
      for (int r = 0; r < 16; ++r) {
        int m = (r & 3) + 8 * (r >> 2) + 4 * h;
        o[(size_t)m * 256] = acc[mf][nf][r];
      }
    }
  #pragma unroll
  for (int nf = 0; nf < 2; ++nf) {
    float s = 0.f, s2 = 0.f;
    #pragma unroll
    for (int mf = 0; mf < 4; ++mf)
      #pragma unroll
      for (int r = 0; r < 16; ++r) {
        float v = acc[mf][nf][r];
        s += v; s2 += v * v;
      }
    s += __shfl_xor(s, 32);
    s2 += __shfl_xor(s2, 32);
    if (lane < 32) {
      part[((size_t)bid * 256 + wid * 64 + nf * 32 + lane) * 2] = s;
      part[((size_t)bid * 256 + wid * 64 + nf * 32 + lane) * 2 + 1] = s2;
    }
  }
  #undef LOADA
  #undef LOADB
}

// ---------------------------------------------------------------- BN stats reduce (grid = 256 channels, 512 slots)
__global__ void stats2(const float* __restrict__ part,
                       const float* __restrict__ g, const float* __restrict__ be,
                       float* __restrict__ sc, float* __restrict__ sh) {
  const int ch = blockIdx.x;
  const int t = threadIdx.x;
  double s = 0.0, s2 = 0.0;
  #pragma unroll
  for (int i = 0; i < 2; ++i) {
    int p = t + i * 256;
    s += (double)part[((size_t)p * 256 + ch) * 2];
    s2 += (double)part[((size_t)p * 256 + ch) * 2 + 1];
  }
  #pragma unroll
  for (int off = 32; off > 0; off >>= 1) {
    s += __shfl_down(s, off);
    s2 += __shfl_down(s2, off);
  }
  __shared__ double ls[4], ls2[4];
  if ((t & 63) == 0) { ls[t >> 6] = s; ls2[t >> 6] = s2; }
  __syncthreads();
  if (t == 0) {
    double S = ls[0] + ls[1] + ls[2] + ls[3];
    double S2 = ls2[0] + ls2[1] + ls2[2] + ls2[3];
    double m = S / 65536.0;
    double var = S2 / 65536.0 - m * m;
    double inv = 1.0 / sqrt(var + 1e-5);
    float scv = (float)inv * g[ch];
    sc[ch] = scv;
    sh[ch] = be[ch] - (float)m * scv;
  }
}

// ---------------------------------------------------------------- BN+relu -> bf16 NHWC
__global__ void bnrelu(const float* __restrict__ T,
                       const float* __restrict__ sc, const float* __restrict__ sh,
                       unsigned short* __restrict__ yB) {
  int i = blockIdx.x * 256 + threadIdx.x;
  float4 v = ((const float4*)T)[i];
  float4 s4 = ((const float4*)sc)[i & 63];
  float4 h4 = ((const float4*)sh)[i & 63];
  short4 o;
  o.x = (short)f2bf(fmaxf(fmaf(v.x, s4.x, h4.x), 0.f));
  o.y = (short)f2bf(fmaxf(fmaf(v.y, s4.y, h4.y), 0.f));
  o.z = (short)f2bf(fmaxf(fmaf(v.z, s4.z, h4.z), 0.f));
  o.w = (short)f2bf(fmaxf(fmaf(v.w, s4.w, h4.w), 0.f));
  ((short4*)yB)[i] = o;
}

// ---------------------------------------------------------------- BN + residual + relu
__global__ void bnres(float* __restrict__ T,
                      const float* __restrict__ sc, const float* __restrict__ sh,
                      unsigned short* __restrict__ xB, int writeT) {
  int i = blockIdx.x * 256 + threadIdx.x;
  float4 v = ((const float4*)T)[i];
  float4 s4 = ((const float4*)sc)[i & 63];
  float4 h4 = ((const float4*)sh)[i & 63];
  short4 rb = ((const short4*)xB)[i];
  float4 o;
  o.x = fmaxf(fmaf(v.x, s4.x, h4.x) + bf2f((unsigned short)rb.x), 0.f);
  o.y = fmaxf(fmaf(v.y, s4.y, h4.y) + bf2f((unsigned short)rb.y), 0.f);
  o.z = fmaxf(fmaf(v.z, s4.z, h4.z) + bf2f((unsigned short)rb.z), 0.f);
  o.w = fmaxf(fmaf(v.w, s4.w, h4.w) + bf2f((unsigned short)rb.w), 0.f);
  short4 ob;
  ob.x = (short)f2bf(o.x); ob.y = (short)f2bf(o.y);
  ob.z = (short)f2bf(o.z); ob.w = (short)f2bf(o.w);
  ((short4*)xB)[i] = ob;
  if (writeT) ((float4*)T)[i] = o;
}

// ---------------------------------------------------------------- NHWC fp32 -> NCHW fp32
__global__ void transpose_k(const float* __restrict__ T, float* __restrict__ out) {
  __shared__ float tl[64][69];
  const int px0 = blockIdx.x * 64;
  const int ch0 = blockIdx.y * 64;
  const int tid = threadIdx.x;
  #pragma unroll
  for (int i = 0; i < 16; ++i) {
    int p = (tid >> 6) + 4 * i;
    int c = tid & 63;
    tl[p][c] = T[(size_t)(px0 + p) * 256 + ch0 + c];
  }
  __syncthreads();
  #pragma unroll
  for (int i = 0; i < 16; ++i) {
    int p = tid & 63;
    int c = (tid >> 6) + 4 * i;
    out[(size_t)(ch0 + c) * HWPX + px0 + p] = tl[p][c];
  }
}

// ----------------------------------------------------------------
extern "C" void kernel_launch(void* const* d_in, const int* in_sizes, int n_in,
                              void* d_out, int out_size, void* d_ws, size_t ws_size,
                              hipStream_t stream) {
  const float* pred_box   = (const float*)d_in[0];
  const float* pred_score = (const float*)d_in[1];
  const float* W1 = (const float*)d_in[2];
  const float* b1 = (const float*)d_in[3];
  const float* W2 = (const float*)d_in[4];
  const float* b2 = (const float*)d_in[5];
  const float* W3 = (const float*)d_in[6];
  const float* b3 = (const float*)d_in[7];
  const float* conv_w = (const float*)d_in[8];
  const float* gamma  = (const float*)d_in[9];
  const float* beta   = (const float*)d_in[10];
  float* out = (float*)d_out;

  char* wsb = (char*)d_ws;
  float* objf = (float*)(wsb + 0);
  int*   bnds = (int*)(wsb + 0x40000);
  float* sc   = (float*)(wsb + 0x42000);
  float* sh   = (float*)(wsb + 0x42400);
  float* part = (float*)(wsb + 0x100000);                               // 1 MB used
  unsigned short* zbuf = (unsigned short*)(wsb + 0x300000);             // 4 KB zeros
  unsigned short* wtAll = (unsigned short*)(wsb + 0x400000);            // 6.75 MB
  unsigned short* xB    = (unsigned short*)(wsb + (size_t)16 * 1024 * 1024);   // 128 MB
  unsigned short* yB    = (unsigned short*)(wsb + (size_t)144 * 1024 * 1024);  // 32 MB
  float* T              = (float*)(wsb + (size_t)176 * 1024 * 1024);           // 64 MB

  const size_t CHW = (size_t)256 * HWPX;

  hipMemsetAsync(zbuf, 0, 4096, stream);
  mlp_kernel<<<128, 256, 0, stream>>>(pred_box, pred_score, W1, b1, W2, b2, W3, b3, objf);
  bounds_kernel<<<1, 128, 0, stream>>>(pred_box, bnds);
  wt_kernel<<<13824, 256, 0, stream>>>(conv_w, wtAll);
  raster_nhwc<<<dim3(256, 4), 256, 0, stream>>>(bnds, objf, xB);

  for (int k = 0; k < 3; ++k) {
    for (int b = 0; b < 4; ++b) {
      unsigned short* xb = xB + (size_t)b * CHW;
      conv_mfma<<<512, 256, 0, stream>>>(xb, wtAll + (size_t)(k * 2 + 0) * 589824, zbuf, T, part);
      stats2<<<256, 256, 0, stream>>>(part, gamma + (k * 2 + 0) * 256, beta + (k * 2 + 0) * 256, sc, sh);
      bnrelu<<<16384, 256, 0, stream>>>(T, sc, sh, yB);
      conv_mfma<<<512, 256, 0, stream>>>(yB, wtAll + (size_t)(k * 2 + 1) * 589824, zbuf, T, part);
      stats2<<<256, 256, 0, stream>>>(part, gamma + (k * 2 + 1) * 256, beta + (k * 2 + 1) * 256, sc, sh);
      bnres<<<16384, 256, 0, stream>>>(T, sc, sh, xb, k == 2 ? 1 : 0);
      if (k == 2) transpose_k<<<dim3(1024, 4), 256, 0, stream>>>(T, out + (size_t)b * CHW);
    }
  }
}

// Round 5
// 2243.914 us; speedup vs baseline: 17.6659x; 1.1046x over previous
//
#include <hip/hip_runtime.h>
#include <hip/hip_bf16.h>

typedef short short8 __attribute__((ext_vector_type(8)));
typedef float f32x16 __attribute__((ext_vector_type(16)));

#define MFMA32 __builtin_amdgcn_mfma_f32_32x32x16_bf16
#define HWPX 65536

#define GLDS16(gp, lp) __builtin_amdgcn_global_load_lds( \
    (const __attribute__((address_space(1))) unsigned int*)(gp), \
    (__attribute__((address_space(3))) unsigned int*)(lp), 16, 0, 0)

__device__ __forceinline__ unsigned short f2bf(float f) {
  unsigned u = __float_as_uint(f);
  u += 0x7FFF + ((u >> 16) & 1);
  return (unsigned short)(u >> 16);
}
__device__ __forceinline__ float bf2f(unsigned short b) {
  return __uint_as_float(((unsigned)b) << 16);
}

// ---------------------------------------------------------------- MLP
__global__ void mlp_kernel(const float* __restrict__ pred_box,
                           const float* __restrict__ score,
                           const float* __restrict__ W1, const float* __restrict__ b1,
                           const float* __restrict__ W2, const float* __restrict__ b2,
                           const float* __restrict__ W3, const float* __restrict__ b3,
                           float* __restrict__ objf) {
  __shared__ float obj[25];
  __shared__ float h1[256];
  __shared__ float h2[256];
  const int box = blockIdx.x;
  const int tid = threadIdx.x;
  if (tid < 24) obj[tid] = pred_box[box * 24 + tid];
  if (tid == 24) obj[24] = score[box];
  __syncthreads();
  float acc = b1[tid];
  #pragma unroll
  for (int k = 0; k < 25; ++k) acc = fmaf(obj[k], W1[k * 256 + tid], acc);
  h1[tid] = fmaxf(acc, 0.f);
  __syncthreads();
  acc = b2[tid];
  #pragma unroll 8
  for (int k = 0; k < 256; ++k) acc = fmaf(h1[k], W2[k * 256 + tid], acc);
  h2[tid] = fmaxf(acc, 0.f);
  __syncthreads();
  acc = b3[tid];
  #pragma unroll 8
  for (int k = 0; k < 256; ++k) acc = fmaf(h2[k], W3[k * 256 + tid], acc);
  objf[box * 256 + tid] = acc * score[box];
}

// ---------------------------------------------------------------- box bounds
__global__ void bounds_kernel(const float* __restrict__ pred_box,
                              int* __restrict__ bnds) {
  const int t = threadIdx.x;
  const float* p = pred_box + t * 24;
  float gx0 = 1e30f, gx1 = -1e30f, gy0 = 1e30f, gy1 = -1e30f;
  #pragma unroll
  for (int j = 0; j < 8; ++j) {
    float gx = floorf((p[j * 3 + 0] + 51.2f) / 0.4f);
    float gy = floorf((p[j * 3 + 1] + 51.2f) / 0.4f);
    gx0 = fminf(gx0, gx); gx1 = fmaxf(gx1, gx);
    gy0 = fminf(gy0, gy); gy1 = fmaxf(gy1, gy);
  }
  bnds[t * 4 + 0] = (int)fminf(fmaxf(gx0, 0.f), 255.f);
  bnds[t * 4 + 1] = (int)fminf(fmaxf(gx1, 0.f), 255.f);
  bnds[t * 4 + 2] = (int)fminf(fmaxf(gy0, 0.f), 255.f);
  bnds[t * 4 + 3] = (int)fminf(fmaxf(gy1, 0.f), 255.f);
}

// ---------------------------------------------------------------- weight transform
// wt2 layout: [cv][tap][kslice(16)][coblk(8)][lane(64)][8ci] bf16 — each MFMA
// B-fragment (tap, 16-K slice, 32-co block) is one contiguous 1KB wave load.
__global__ void wt_kernel(const float* __restrict__ w, unsigned short* __restrict__ wt) {
  int i = blockIdx.x * 256 + threadIdx.x;          // 6*9*16*8*512 = 3,538,944
  int j = i & 7;
  int l = (i >> 3) & 63;
  int nb = (i >> 9) & 7;
  int ks = (i >> 12) & 15;
  int t2 = i >> 16;
  int tap = t2 % 9;
  int cv = t2 / 9;
  int co = nb * 32 + (l & 31);
  int ci = ks * 16 + ((l >> 5) << 3) + j;
  wt[i] = f2bf(w[(size_t)((cv * 256 + co) * 256 + ci) * 9 + tap]);
}

// ---------------------------------------------------------------- raster -> NHWC bf16
__global__ void raster_nhwc(const int* __restrict__ bnds,
                            const float* __restrict__ objf,
                            unsigned short* __restrict__ xB) {
  const int y = blockIdx.x;
  const int b = blockIdx.y;
  const int x = threadIdx.x;
  __shared__ int sb[128];
  __shared__ int lastA[256];
  if (x < 128) sb[x] = bnds[b * 128 + x];
  __syncthreads();
  int last = -1;
  #pragma unroll
  for (int n = 0; n < 32; ++n) {
    int bx0 = sb[n * 4 + 0], bx1 = sb[n * 4 + 1];
    int by0 = sb[n * 4 + 2], by1 = sb[n * 4 + 3];
    if (x >= bx0 && x <= bx1 && y >= by0 && y <= by1) last = n;
  }
  lastA[x] = last;
  __syncthreads();
  unsigned short* row = xB + ((size_t)b * HWPX + y * 256) * 256;
  for (int it = 0; it < 32; ++it) {
    int s = x + 256 * it;
    int px = s >> 5;
    int c8 = (s & 31) * 8;
    int ln = lastA[px];
    short8 v = {0, 0, 0, 0, 0, 0, 0, 0};
    if (ln >= 0) {
      const float* f = objf + (b * 32 + ln) * 256 + c8;
      #pragma unroll
      for (int j = 0; j < 8; ++j) v[j] = (short)f2bf(f[j]);
    }
    *(short8*)(row + px * 256 + c8) = v;
  }
}

// ---------------------------------------------------------------- implicit-GEMM conv 3x3, bf16 MFMA 32x32x16
// grid 2048 (4 batches x 512 tiles), XCD-swizzled. Block tile = 2 rows x 64 px x 256 co.
// 4 waves = 4 co-quarters; wave = 128 px x 64 co, acc[4][2] f32x16.
// Output written as bf16 NHWC; BN partials (fp32 acc) per block.
__global__ __launch_bounds__(256, 2) void conv_mfma(const unsigned short* __restrict__ in,
                                                    const unsigned short* __restrict__ wt,
                                                    const unsigned short* __restrict__ zbuf,
                                                    unsigned short* __restrict__ T,
                                                    float* __restrict__ part) {
  __shared__ unsigned short lds[2][16 * 528];
  const int bid0 = blockIdx.x;
  const int swz = (bid0 & 7) * 256 + (bid0 >> 3);    // 2048 = 8*256, bijective
  const int b = swz >> 9;
  const int bid = swz & 511;
  const int x0 = (bid & 3) * 64;
  const int y0 = (bid >> 2) * 2;
  const int tid = threadIdx.x;
  const int lane = tid & 63;
  const int wid = tid >> 6;                            // co-quarter
  const int h = lane >> 5;
  const int l31 = lane & 31;
  const int col0 = l31 * 8;

  const unsigned short* inb = in + (size_t)b * (HWPX * 256);
  unsigned short* Tb = T + (size_t)b * (HWPX * 256);

  f32x16 acc[4][2];
  #pragma unroll
  for (int a = 0; a < 4; ++a)
    #pragma unroll
    for (int n = 0; n < 2; ++n)
      #pragma unroll
      for (int r = 0; r < 16; ++r) acc[a][n][r] = 0.f;

  const unsigned short* wbase = wt + (size_t)(wid * 2) * 512 + lane * 8;

  short8 edgev;

  auto stage = [&](int c1, int buf) {
    const int ci0 = c1 * 32;
    #pragma unroll
    for (int i = 0; i < 4; ++i) {
      const int rowg = wid * 4 + i;
      const int row = rowg >> 2;
      const int g = rowg & 3;
      const int yg = y0 + row - 1;
      unsigned short* lp = &lds[buf][((row << 2) | ((g & 1) << 1) | (g >> 1)) * 528 + 8];
      const unsigned short* gp;
      if ((unsigned)yg < 256u)
        gp = inb + ((size_t)(yg * 256 + x0 + lane) * 256 + ci0 + g * 8);
      else
        gp = zbuf + lane * 8;
      GLDS16(gp, lp);
    }
  };

  auto edge_load = [&](int c1) {
    edgev = (short8){0, 0, 0, 0, 0, 0, 0, 0};
    if (tid < 32) {
      int row = tid >> 3, side = (tid >> 2) & 1, g = tid & 3;
      int yg = y0 + row - 1;
      int xg = x0 + (side ? 64 : -1);
      if ((unsigned)yg < 256u && (unsigned)xg < 256u)
        edgev = *(const short8*)(inb + ((size_t)(yg * 256 + xg) * 256 + c1 * 32 + g * 8));
    }
  };
  auto edge_store = [&](int buf) {
    if (tid < 32) {
      int row = tid >> 3, side = (tid >> 2) & 1, g = tid & 3;
      *(short8*)&lds[buf][((row << 2) | ((g & 1) << 1) | (g >> 1)) * 528 + (side ? 65 : 0) * 8] = edgev;
    }
  };

  #define LOADA(s, d) { \
    const int ks_ = (s) / 9, tap_ = (s) % 9, ky_ = tap_ / 3, kx_ = tap_ % 3; \
    const unsigned short* p_ = lbase + ky_ * 2112 + ks_ * 528 + kx_ * 8 + col0; \
    d[0] = *(const short8*)(p_); \
    d[1] = *(const short8*)(p_ + 256); \
    d[2] = *(const short8*)(p_ + 2112); \
    d[3] = *(const short8*)(p_ + 2368); }

  #define LOADB(s, d) { \
    const unsigned short* p_ = wbase + (size_t)((((s) % 9) * 16 + c * 2 + (s) / 9) * 8) * 512; \
    d[0] = *(const short8*)(p_); d[1] = *(const short8*)(p_ + 512); }

  auto compute = [&](int buf, int c) {
    const unsigned short* lbase = &lds[buf][h * 1056];
    short8 Af[2][4];
    short8 Bf[3][2];
    LOADA(0, Af[0]);
    LOADB(0, Bf[0]);
    LOADB(1, Bf[1]);
    #pragma unroll
    for (int s = 0; s < 18; ++s) {
      if (s + 2 < 18) LOADB(s + 2, Bf[(s + 2) % 3]);
      if (s + 1 < 18) LOADA(s + 1, Af[(s + 1) & 1]);
      #pragma unroll
      for (int mf = 0; mf < 4; ++mf)
        #pragma unroll
        for (int nf = 0; nf < 2; ++nf)
          acc[mf][nf] = MFMA32(Af[s & 1][mf], Bf[s % 3][nf], acc[mf][nf], 0, 0, 0);
    }
  };

  stage(0, 0);
  edge_load(0);
  edge_store(0);
  __syncthreads();
  int cur = 0;
  for (int c = 0; c < 8; ++c) {
    if (c < 7) { stage(c + 1, cur ^ 1); edge_load(c + 1); }
    compute(cur, c);
    if (c < 7) edge_store(cur ^ 1);
    __syncthreads();
    cur ^= 1;
  }

  // epilogue: bf16 NHWC store + fp32 BN partial sums
  #pragma unroll
  for (int mf = 0; mf < 4; ++mf)
    #pragma unroll
    for (int nf = 0; nf < 2; ++nf) {
      unsigned short* o = Tb + ((size_t)((y0 + (mf >> 1)) * 256) + x0 + (mf & 1) * 32) * 256
                          + wid * 64 + nf * 32 + l31;
      #pragma unroll
      for (int r = 0; r < 16; ++r) {
        int m = (r & 3) + 8 * (r >> 2) + 4 * h;
        o[(size_t)m * 256] = f2bf(acc[mf][nf][r]);
      }
    }
  #pragma unroll
  for (int nf = 0; nf < 2; ++nf) {
    float s = 0.f, s2 = 0.f;
    #pragma unroll
    for (int mf = 0; mf < 4; ++mf)
      #pragma unroll
      for (int r = 0; r < 16; ++r) {
        float v = acc[mf][nf][r];
        s += v; s2 += v * v;
      }
    s += __shfl_xor(s, 32);
    s2 += __shfl_xor(s2, 32);
    if (lane < 32) {
      part[((size_t)swz * 256 + wid * 64 + nf * 32 + lane) * 2] = s;
      part[((size_t)swz * 256 + wid * 64 + nf * 32 + lane) * 2 + 1] = s2;
    }
  }
  #undef LOADA
  #undef LOADB
}

// ---------------------------------------------------------------- BN stats reduce, grid (256 ch, 4 b)
__global__ void stats2(const float* __restrict__ part,
                       const float* __restrict__ g, const float* __restrict__ be,
                       float* __restrict__ sc, float* __restrict__ sh) {
  const int ch = blockIdx.x;
  const int b = blockIdx.y;
  const int t = threadIdx.x;
  double s = 0.0, s2 = 0.0;
  #pragma unroll
  for (int i = 0; i < 2; ++i) {
    int p = b * 512 + t + i * 256;
    s += (double)part[((size_t)p * 256 + ch) * 2];
    s2 += (double)part[((size_t)p * 256 + ch) * 2 + 1];
  }
  #pragma unroll
  for (int off = 32; off > 0; off >>= 1) {
    s += __shfl_down(s, off);
    s2 += __shfl_down(s2, off);
  }
  __shared__ double ls[4], ls2[4];
  if ((t & 63) == 0) { ls[t >> 6] = s; ls2[t >> 6] = s2; }
  __syncthreads();
  if (t == 0) {
    double S = ls[0] + ls[1] + ls[2] + ls[3];
    double S2 = ls2[0] + ls2[1] + ls2[2] + ls2[3];
    double m = S / 65536.0;
    double var = S2 / 65536.0 - m * m;
    double inv = 1.0 / sqrt(var + 1e-5);
    float scv = (float)inv * g[ch];
    sc[b * 256 + ch] = scv;
    sh[b * 256 + ch] = be[ch] - (float)m * scv;
  }
}

// ---------------------------------------------------------------- BN+relu: bf16 T -> bf16 yB (all batches)
__global__ void bnrelu(const unsigned short* __restrict__ T,
                       const float* __restrict__ sc, const float* __restrict__ sh,
                       unsigned short* __restrict__ yB) {
  #pragma unroll
  for (int it = 0; it < 8; ++it) {
    size_t e = (size_t)it * 1048576 + blockIdx.x * 256 + threadIdx.x;  // short8 idx
    int b = (int)(e >> 21);
    int ch8 = (int)(e & 31);
    const float* scp = sc + b * 256 + ch8 * 8;
    const float* shp = sh + b * 256 + ch8 * 8;
    float4 s0 = ((const float4*)scp)[0], s1 = ((const float4*)scp)[1];
    float4 h0 = ((const float4*)shp)[0], h1 = ((const float4*)shp)[1];
    float scv[8] = {s0.x, s0.y, s0.z, s0.w, s1.x, s1.y, s1.z, s1.w};
    float shv[8] = {h0.x, h0.y, h0.z, h0.w, h1.x, h1.y, h1.z, h1.w};
    short8 v = ((const short8*)T)[e];
    short8 o;
    #pragma unroll
    for (int j = 0; j < 8; ++j)
      o[j] = (short)f2bf(fmaxf(fmaf(bf2f((unsigned short)v[j]), scv[j], shv[j]), 0.f));
    ((short8*)yB)[e] = o;
  }
}

// ---------------------------------------------------------------- BN + residual + relu -> xB bf16 (k<2)
__global__ void bnres(const unsigned short* __restrict__ T,
                      const float* __restrict__ sc, const float* __restrict__ sh,
                      unsigned short* __restrict__ xB) {
  #pragma unroll
  for (int it = 0; it < 8; ++it) {
    size_t e = (size_t)it * 1048576 + blockIdx.x * 256 + threadIdx.x;
    int b = (int)(e >> 21);
    int ch8 = (int)(e & 31);
    const float* scp = sc + b * 256 + ch8 * 8;
    const float* shp = sh + b * 256 + ch8 * 8;
    float4 s0 = ((const float4*)scp)[0], s1 = ((const float4*)scp)[1];
    float4 h0 = ((const float4*)shp)[0], h1 = ((const float4*)shp)[1];
    float scv[8] = {s0.x, s0.y, s0.z, s0.w, s1.x, s1.y, s1.z, s1.w};
    float shv[8] = {h0.x, h0.y, h0.z, h0.w, h1.x, h1.y, h1.z, h1.w};
    short8 v = ((const short8*)T)[e];
    short8 rb = ((const short8*)xB)[e];
    short8 o;
    #pragma unroll
    for (int j = 0; j < 8; ++j) {
      float f = fmaf(bf2f((unsigned short)v[j]), scv[j], shv[j]) + bf2f((unsigned short)rb[j]);
      o[j] = (short)f2bf(fmaxf(f, 0.f));
    }
    ((short8*)xB)[e] = o;
  }
}

// ---------------------------------------------------------------- final: BN + residual + relu + NHWC->NCHW fp32
// grid (4096, 4): bx -> pxb (64px), chb (64ch); by = batch.
__global__ void bnres_tr(const unsigned short* __restrict__ T,
                         const float* __restrict__ sc, const float* __restrict__ sh,
                         const unsigned short* __restrict__ xB,
                         float* __restrict__ out) {
  __shared__ float tl[64][65];
  const int pxb = blockIdx.x >> 2;
  const int chb = blockIdx.x & 3;
  const int b = blockIdx.y;
  const int px0 = pxb * 64;
  const int ch0 = chb * 64;
  const int tid = threadIdx.x;
  #pragma unroll
  for (int i = 0; i < 2; ++i) {
    int p = (tid >> 3) + 32 * i;
    int c8 = (tid & 7) * 8;
    size_t e = ((size_t)b * HWPX + px0 + p) * 256 + ch0 + c8;
    const float* scp = sc + b * 256 + ch0 + c8;
    const float* shp = sh + b * 256 + ch0 + c8;
    float4 s0 = ((const float4*)scp)[0], s1 = ((const float4*)scp)[1];
    float4 h0 = ((const float4*)shp)[0], h1 = ((const float4*)shp)[1];
    float scv[8] = {s0.x, s0.y, s0.z, s0.w, s1.x, s1.y, s1.z, s1.w};
    float shv[8] = {h0.x, h0.y, h0.z, h0.w, h1.x, h1.y, h1.z, h1.w};
    short8 v = *(const short8*)(T + e);
    short8 rb = *(const short8*)(xB + e);
    #pragma unroll
    for (int j = 0; j < 8; ++j) {
      float f = fmaf(bf2f((unsigned short)v[j]), scv[j], shv[j]) + bf2f((unsigned short)rb[j]);
      tl[p][c8 + j] = fmaxf(f, 0.f);
    }
  }
  __syncthreads();
  float* ob = out + (size_t)b * (HWPX * 256);
  #pragma unroll
  for (int i = 0; i < 16; ++i) {
    int c = (tid >> 6) + 4 * i;
    int p = tid & 63;
    ob[(size_t)(ch0 + c) * HWPX + px0 + p] = tl[p][c];
  }
}

// ----------------------------------------------------------------
extern "C" void kernel_launch(void* const* d_in, const int* in_sizes, int n_in,
                              void* d_out, int out_size, void* d_ws, size_t ws_size,
                              hipStream_t stream) {
  const float* pred_box   = (const float*)d_in[0];
  const float* pred_score = (const float*)d_in[1];
  const float* W1 = (const float*)d_in[2];
  const float* b1 = (const float*)d_in[3];
  const float* W2 = (const float*)d_in[4];
  const float* b2 = (const float*)d_in[5];
  const float* W3 = (const float*)d_in[6];
  const float* b3 = (const float*)d_in[7];
  const float* conv_w = (const float*)d_in[8];
  const float* gamma  = (const float*)d_in[9];
  const float* beta   = (const float*)d_in[10];
  float* out = (float*)d_out;

  char* wsb = (char*)d_ws;
  float* objf = (float*)(wsb + 0);                                      // 128 KB
  int*   bnds = (int*)(wsb + 0x40000);
  float* sc   = (float*)(wsb + 0x42000);                                // 4 KB
  float* sh   = (float*)(wsb + 0x44000);                                // 4 KB
  float* part = (float*)(wsb + 0x100000);                               // 4 MB
  unsigned short* zbuf = (unsigned short*)(wsb + 0x500000);             // 4 KB zeros
  unsigned short* wtAll = (unsigned short*)(wsb + 0x600000);            // 6.75 MB
  unsigned short* xB = (unsigned short*)(wsb + (size_t)16 * 1024 * 1024);   // 134 MB
  unsigned short* yB = (unsigned short*)(wsb + (size_t)160 * 1024 * 1024);  // 134 MB
  unsigned short* T  = (unsigned short*)(wsb + (size_t)304 * 1024 * 1024);  // 134 MB

  hipMemsetAsync(zbuf, 0, 4096, stream);
  mlp_kernel<<<128, 256, 0, stream>>>(pred_box, pred_score, W1, b1, W2, b2, W3, b3, objf);
  bounds_kernel<<<1, 128, 0, stream>>>(pred_box, bnds);
  wt_kernel<<<13824, 256, 0, stream>>>(conv_w, wtAll);
  raster_nhwc<<<dim3(256, 4), 256, 0, stream>>>(bnds, objf, xB);

  for (int k = 0; k < 3; ++k) {
    const unsigned short* wk0 = wtAll + (size_t)(k * 2 + 0) * 589824;
    const unsigned short* wk1 = wtAll + (size_t)(k * 2 + 1) * 589824;
    conv_mfma<<<2048, 256, 0, stream>>>(xB, wk0, zbuf, T, part);
    stats2<<<dim3(256, 4), 256, 0, stream>>>(part, gamma + (k * 2 + 0) * 256,
                                             beta + (k * 2 + 0) * 256, sc, sh);
    bnrelu<<<4096, 256, 0, stream>>>(T, sc, sh, yB);
    conv_mfma<<<2048, 256, 0, stream>>>(yB, wk1, zbuf, T, part);
    stats2<<<dim3(256, 4), 256, 0, stream>>>(part, gamma + (k * 2 + 1) * 256,
                                             beta + (k * 2 + 1) * 256, sc, sh);
    if (k < 2)
      bnres<<<4096, 256, 0, stream>>>(T, sc, sh, xB);
    else
      bnres_tr<<<dim3(4096, 4), 256, 0, stream>>>(T, sc, sh, xB, out);
  }
}

// Round 6
// 1969.124 us; speedup vs baseline: 20.1311x; 1.1395x over previous
//
#include <hip/hip_runtime.h>
#include <hip/hip_bf16.h>

typedef short short8 __attribute__((ext_vector_type(8)));
typedef float f32x16 __attribute__((ext_vector_type(16)));

#define MFMA32 __builtin_amdgcn_mfma_f32_32x32x16_bf16
#define HWPX 65536

#define GLDS16(gp, lp) __builtin_amdgcn_global_load_lds( \
    (const __attribute__((address_space(1))) unsigned int*)(gp), \
    (__attribute__((address_space(3))) unsigned int*)(lp), 16, 0, 0)

__device__ __forceinline__ unsigned short f2bf(float f) {
  unsigned u = __float_as_uint(f);
  u += 0x7FFF + ((u >> 16) & 1);
  return (unsigned short)(u >> 16);
}
__device__ __forceinline__ float bf2f(unsigned short b) {
  return __uint_as_float(((unsigned)b) << 16);
}

// ---------------------------------------------------------------- MLP
__global__ void mlp_kernel(const float* __restrict__ pred_box,
                           const float* __restrict__ score,
                           const float* __restrict__ W1, const float* __restrict__ b1,
                           const float* __restrict__ W2, const float* __restrict__ b2,
                           const float* __restrict__ W3, const float* __restrict__ b3,
                           float* __restrict__ objf) {
  __shared__ float obj[25];
  __shared__ float h1[256];
  __shared__ float h2[256];
  const int box = blockIdx.x;
  const int tid = threadIdx.x;
  if (tid < 24) obj[tid] = pred_box[box * 24 + tid];
  if (tid == 24) obj[24] = score[box];
  __syncthreads();
  float acc = b1[tid];
  #pragma unroll
  for (int k = 0; k < 25; ++k) acc = fmaf(obj[k], W1[k * 256 + tid], acc);
  h1[tid] = fmaxf(acc, 0.f);
  __syncthreads();
  acc = b2[tid];
  #pragma unroll 8
  for (int k = 0; k < 256; ++k) acc = fmaf(h1[k], W2[k * 256 + tid], acc);
  h2[tid] = fmaxf(acc, 0.f);
  __syncthreads();
  acc = b3[tid];
  #pragma unroll 8
  for (int k = 0; k < 256; ++k) acc = fmaf(h2[k], W3[k * 256 + tid], acc);
  objf[box * 256 + tid] = acc * score[box];
}

// ---------------------------------------------------------------- box bounds
__global__ void bounds_kernel(const float* __restrict__ pred_box,
                              int* __restrict__ bnds) {
  const int t = threadIdx.x;
  const float* p = pred_box + t * 24;
  float gx0 = 1e30f, gx1 = -1e30f, gy0 = 1e30f, gy1 = -1e30f;
  #pragma unroll
  for (int j = 0; j < 8; ++j) {
    float gx = floorf((p[j * 3 + 0] + 51.2f) / 0.4f);
    float gy = floorf((p[j * 3 + 1] + 51.2f) / 0.4f);
    gx0 = fminf(gx0, gx); gx1 = fmaxf(gx1, gx);
    gy0 = fminf(gy0, gy); gy1 = fmaxf(gy1, gy);
  }
  bnds[t * 4 + 0] = (int)fminf(fmaxf(gx0, 0.f), 255.f);
  bnds[t * 4 + 1] = (int)fminf(fmaxf(gx1, 0.f), 255.f);
  bnds[t * 4 + 2] = (int)fminf(fmaxf(gy0, 0.f), 255.f);
  bnds[t * 4 + 3] = (int)fminf(fmaxf(gy1, 0.f), 255.f);
}

// ---------------------------------------------------------------- weight transform
// wt2 layout: [cv][tap][kslice(16)][coblk(8)][lane(64)][8ci] bf16 — each MFMA
// B-fragment (tap, 16-K slice, 32-co block) is one contiguous 1KB wave load.
__global__ void wt_kernel(const float* __restrict__ w, unsigned short* __restrict__ wt) {
  int i = blockIdx.x * 256 + threadIdx.x;          // 6*9*16*8*512 = 3,538,944
  int j = i & 7;
  int l = (i >> 3) & 63;
  int nb = (i >> 9) & 7;
  int ks = (i >> 12) & 15;
  int t2 = i >> 16;
  int tap = t2 % 9;
  int cv = t2 / 9;
  int co = nb * 32 + (l & 31);
  int ci = ks * 16 + ((l >> 5) << 3) + j;
  wt[i] = f2bf(w[(size_t)((cv * 256 + co) * 256 + ci) * 9 + tap]);
}

// ---------------------------------------------------------------- raster -> NHWC bf16
__global__ void raster_nhwc(const int* __restrict__ bnds,
                            const float* __restrict__ objf,
                            unsigned short* __restrict__ xB) {
  const int y = blockIdx.x;
  const int b = blockIdx.y;
  const int x = threadIdx.x;
  __shared__ int sb[128];
  __shared__ int lastA[256];
  if (x < 128) sb[x] = bnds[b * 128 + x];
  __syncthreads();
  int last = -1;
  #pragma unroll
  for (int n = 0; n < 32; ++n) {
    int bx0 = sb[n * 4 + 0], bx1 = sb[n * 4 + 1];
    int by0 = sb[n * 4 + 2], by1 = sb[n * 4 + 3];
    if (x >= bx0 && x <= bx1 && y >= by0 && y <= by1) last = n;
  }
  lastA[x] = last;
  __syncthreads();
  unsigned short* row = xB + ((size_t)b * HWPX + y * 256) * 256;
  for (int it = 0; it < 32; ++it) {
    int s = x + 256 * it;
    int px = s >> 5;
    int c8 = (s & 31) * 8;
    int ln = lastA[px];
    short8 v = {0, 0, 0, 0, 0, 0, 0, 0};
    if (ln >= 0) {
      const float* f = objf + (b * 32 + ln) * 256 + c8;
      #pragma unroll
      for (int j = 0; j < 8; ++j) v[j] = (short)f2bf(f[j]);
    }
    *(short8*)(row + px * 256 + c8) = v;
  }
}

// ---------------------------------------------------------------- implicit-GEMM conv 3x3, bf16 MFMA 32x32x16
// grid 2048 (4 batches x 512 tiles), XCD-swizzled. Block tile = 2 rows x 64 px x 256 co.
// 4 waves = 4 co-quarters; wave = 128 px x 64 co, acc[4][2] f32x16.
// T4 counted-vmcnt schedule: raw s_barrier + vmcnt(8) — stage loads span
// barriers, never drained to 0 in the main loop. T5 setprio around MFMA bursts.
__global__ __launch_bounds__(256, 2) void conv_mfma(const unsigned short* __restrict__ in,
                                                    const unsigned short* __restrict__ wt,
                                                    const unsigned short* __restrict__ zbuf,
                                                    unsigned short* __restrict__ T,
                                                    float* __restrict__ part) {
  __shared__ unsigned short lds[2][16 * 528];
  const int bid0 = blockIdx.x;
  const int swz = (bid0 & 7) * 256 + (bid0 >> 3);    // 2048 = 8*256, bijective
  const int b = swz >> 9;
  const int bid = swz & 511;
  const int x0 = (bid & 3) * 64;
  const int y0 = (bid >> 2) * 2;
  const int tid = threadIdx.x;
  const int lane = tid & 63;
  const int wid = tid >> 6;                            // co-quarter
  const int h = lane >> 5;
  const int l31 = lane & 31;
  const int col0 = l31 * 8;

  const unsigned short* inb = in + (size_t)b * (HWPX * 256);
  unsigned short* Tb = T + (size_t)b * (HWPX * 256);

  f32x16 acc[4][2];
  #pragma unroll
  for (int a = 0; a < 4; ++a)
    #pragma unroll
    for (int n = 0; n < 2; ++n)
      #pragma unroll
      for (int r = 0; r < 16; ++r) acc[a][n][r] = 0.f;

  const unsigned short* wbase = wt + (size_t)(wid * 2) * 512 + lane * 8;

  short8 edgev;

  auto stage = [&](int c1, int buf) {
    const int ci0 = c1 * 32;
    #pragma unroll
    for (int i = 0; i < 4; ++i) {
      const int rowg = wid * 4 + i;
      const int row = rowg >> 2;
      const int g = rowg & 3;
      const int yg = y0 + row - 1;
      unsigned short* lp = &lds[buf][((row << 2) | ((g & 1) << 1) | (g >> 1)) * 528 + 8];
      const unsigned short* gp;
      if ((unsigned)yg < 256u)
        gp = inb + ((size_t)(yg * 256 + x0 + lane) * 256 + ci0 + g * 8);
      else
        gp = zbuf + lane * 8;
      GLDS16(gp, lp);
    }
  };

  auto edge_load = [&](int c1) {
    edgev = (short8){0, 0, 0, 0, 0, 0, 0, 0};
    if (tid < 32) {
      int row = tid >> 3, side = (tid >> 2) & 1, g = tid & 3;
      int yg = y0 + row - 1;
      int xg = x0 + (side ? 64 : -1);
      if ((unsigned)yg < 256u && (unsigned)xg < 256u)
        edgev = *(const short8*)(inb + ((size_t)(yg * 256 + xg) * 256 + c1 * 32 + g * 8));
    }
  };
  auto edge_store = [&](int buf) {
    if (tid < 32) {
      int row = tid >> 3, side = (tid >> 2) & 1, g = tid & 3;
      *(short8*)&lds[buf][((row << 2) | ((g & 1) << 1) | (g >> 1)) * 528 + (side ? 65 : 0) * 8] = edgev;
    }
  };

  #define LOADA(s, d) { \
    const int ks_ = (s) / 9, tap_ = (s) % 9, ky_ = tap_ / 3, kx_ = tap_ % 3; \
    const unsigned short* p_ = lbase + ky_ * 2112 + ks_ * 528 + kx_ * 8 + col0; \
    d[0] = *(const short8*)(p_); \
    d[1] = *(const short8*)(p_ + 256); \
    d[2] = *(const short8*)(p_ + 2112); \
    d[3] = *(const short8*)(p_ + 2368); }

  #define LOADB(s, d) { \
    const unsigned short* p_ = wbase + (size_t)((((s) % 9) * 16 + c * 2 + (s) / 9) * 8) * 512; \
    d[0] = *(const short8*)(p_); d[1] = *(const short8*)(p_ + 512); }

  auto compute = [&](int buf, int c) {
    const unsigned short* lbase = &lds[buf][h * 1056];
    short8 Af[2][4];
    short8 Bf[3][2];
    LOADA(0, Af[0]);
    LOADB(0, Bf[0]);
    LOADB(1, Bf[1]);
    #pragma unroll
    for (int s = 0; s < 18; ++s) {
      if (s + 2 < 18) LOADB(s + 2, Bf[(s + 2) % 3]);
      if (s + 1 < 18) LOADA(s + 1, Af[(s + 1) & 1]);
      __builtin_amdgcn_s_setprio(1);
      #pragma unroll
      for (int mf = 0; mf < 4; ++mf)
        #pragma unroll
        for (int nf = 0; nf < 2; ++nf)
          acc[mf][nf] = MFMA32(Af[s & 1][mf], Bf[s % 3][nf], acc[mf][nf], 0, 0, 0);
      __builtin_amdgcn_s_setprio(0);
    }
  };

  // prologue: stage chunk 0, fill its edges; edge ds_write drained before first barrier
  stage(0, 0);
  edge_load(0);
  edge_store(0);
  asm volatile("s_waitcnt lgkmcnt(0)" ::: "memory");

  int cur = 0;
  for (int c = 0; c < 8; ++c) {
    // (a) issue next-chunk stage into cur^1 — safe: barrier #2 of previous
    //     iteration guarantees all waves finished reading cur^1 (chunk c-1).
    if (c < 7) {
      stage(c + 1, cur ^ 1);
      // (b) own stage(c) retired; stage(c+1)'s 8 loads stay in flight.
      asm volatile("s_waitcnt vmcnt(8)" ::: "memory");
    } else {
      asm volatile("s_waitcnt vmcnt(0)" ::: "memory");
    }
    // (c) barrier #1: every wave's stage(c) data is in LDS -> chunk c readable
    __builtin_amdgcn_s_barrier();
    if (c < 7) edge_load(c + 1);          // latency hides under compute
    compute(cur, c);
    if (c < 7) edge_store(cur ^ 1);       // disjoint from stage(c+1) slots
    // (e/f) edge ds_write drained, then barrier #2: all reads of cur done
    asm volatile("s_waitcnt lgkmcnt(0)" ::: "memory");
    __builtin_amdgcn_s_barrier();
    cur ^= 1;
  }

  // epilogue: bf16 NHWC store + fp32 BN partial sums
  #pragma unroll
  for (int mf = 0; mf < 4; ++mf)
    #pragma unroll
    for (int nf = 0; nf < 2; ++nf) {
      unsigned short* o = Tb + ((size_t)((y0 + (mf >> 1)) * 256) + x0 + (mf & 1) * 32) * 256
                          + wid * 64 + nf * 32 + l31;
      #pragma unroll
      for (int r = 0; r < 16; ++r) {
        int m = (r & 3) + 8 * (r >> 2) + 4 * h;
        o[(size_t)m * 256] = f2bf(acc[mf][nf][r]);
      }
    }
  #pragma unroll
  for (int nf = 0; nf < 2; ++nf) {
    float s = 0.f, s2 = 0.f;
    #pragma unroll
    for (int mf = 0; mf < 4; ++mf)
      #pragma unroll
      for (int r = 0; r < 16; ++r) {
        float v = acc[mf][nf][r];
        s += v; s2 += v * v;
      }
    s += __shfl_xor(s, 32);
    s2 += __shfl_xor(s2, 32);
    if (lane < 32) {
      part[((size_t)swz * 256 + wid * 64 + nf * 32 + lane) * 2] = s;
      part[((size_t)swz * 256 + wid * 64 + nf * 32 + lane) * 2 + 1] = s2;
    }
  }
  #undef LOADA
  #undef LOADB
}

// ---------------------------------------------------------------- BN stats reduce, grid (256 ch, 4 b)
__global__ void stats2(const float* __restrict__ part,
                       const float* __restrict__ g, const float* __restrict__ be,
                       float* __restrict__ sc, float* __restrict__ sh) {
  const int ch = blockIdx.x;
  const int b = blockIdx.y;
  const int t = threadIdx.x;
  double s = 0.0, s2 = 0.0;
  #pragma unroll
  for (int i = 0; i < 2; ++i) {
    int p = b * 512 + t + i * 256;
    s += (double)part[((size_t)p * 256 + ch) * 2];
    s2 += (double)part[((size_t)p * 256 + ch) * 2 + 1];
  }
  #pragma unroll
  for (int off = 32; off > 0; off >>= 1) {
    s += __shfl_down(s, off);
    s2 += __shfl_down(s2, off);
  }
  __shared__ double ls[4], ls2[4];
  if ((t & 63) == 0) { ls[t >> 6] = s; ls2[t >> 6] = s2; }
  __syncthreads();
  if (t == 0) {
    double S = ls[0] + ls[1] + ls[2] + ls[3];
    double S2 = ls2[0] + ls2[1] + ls2[2] + ls2[3];
    double m = S / 65536.0;
    double var = S2 / 65536.0 - m * m;
    double inv = 1.0 / sqrt(var + 1e-5);
    float scv = (float)inv * g[ch];
    sc[b * 256 + ch] = scv;
    sh[b * 256 + ch] = be[ch] - (float)m * scv;
  }
}

// ---------------------------------------------------------------- BN+relu: bf16 T -> bf16 yB (all batches)
__global__ void bnrelu(const unsigned short* __restrict__ T,
                       const float* __restrict__ sc, const float* __restrict__ sh,
                       unsigned short* __restrict__ yB) {
  #pragma unroll
  for (int it = 0; it < 8; ++it) {
    size_t e = (size_t)it * 1048576 + blockIdx.x * 256 + threadIdx.x;  // short8 idx
    int b = (int)(e >> 21);
    int ch8 = (int)(e & 31);
    const float* scp = sc + b * 256 + ch8 * 8;
    const float* shp = sh + b * 256 + ch8 * 8;
    float4 s0 = ((const float4*)scp)[0], s1 = ((const float4*)scp)[1];
    float4 h0 = ((const float4*)shp)[0], h1 = ((const float4*)shp)[1];
    float scv[8] = {s0.x, s0.y, s0.z, s0.w, s1.x, s1.y, s1.z, s1.w};
    float shv[8] = {h0.x, h0.y, h0.z, h0.w, h1.x, h1.y, h1.z, h1.w};
    short8 v = ((const short8*)T)[e];
    short8 o;
    #pragma unroll
    for (int j = 0; j < 8; ++j)
      o[j] = (short)f2bf(fmaxf(fmaf(bf2f((unsigned short)v[j]), scv[j], shv[j]), 0.f));
    ((short8*)yB)[e] = o;
  }
}

// ---------------------------------------------------------------- BN + residual + relu -> xB bf16 (k<2)
__global__ void bnres(const unsigned short* __restrict__ T,
                      const float* __restrict__ sc, const float* __restrict__ sh,
                      unsigned short* __restrict__ xB) {
  #pragma unroll
  for (int it = 0; it < 8; ++it) {
    size_t e = (size_t)it * 1048576 + blockIdx.x * 256 + threadIdx.x;
    int b = (int)(e >> 21);
    int ch8 = (int)(e & 31);
    const float* scp = sc + b * 256 + ch8 * 8;
    const float* shp = sh + b * 256 + ch8 * 8;
    float4 s0 = ((const float4*)scp)[0], s1 = ((const float4*)scp)[1];
    float4 h0 = ((const float4*)shp)[0], h1 = ((const float4*)shp)[1];
    float scv[8] = {s0.x, s0.y, s0.z, s0.w, s1.x, s1.y, s1.z, s1.w};
    float shv[8] = {h0.x, h0.y, h0.z, h0.w, h1.x, h1.y, h1.z, h1.w};
    short8 v = ((const short8*)T)[e];
    short8 rb = ((const short8*)xB)[e];
    short8 o;
    #pragma unroll
    for (int j = 0; j < 8; ++j) {
      float f = fmaf(bf2f((unsigned short)v[j]), scv[j], shv[j]) + bf2f((unsigned short)rb[j]);
      o[j] = (short)f2bf(fmaxf(f, 0.f));
    }
    ((short8*)xB)[e] = o;
  }
}

// ---------------------------------------------------------------- final: BN + residual + relu + NHWC->NCHW fp32
// grid (4096, 4): bx -> pxb (64px), chb (64ch); by = batch.
__global__ void bnres_tr(const unsigned short* __restrict__ T,
                         const float* __restrict__ sc, const float* __restrict__ sh,
                         const unsigned short* __restrict__ xB,
                         float* __restrict__ out) {
  __shared__ float tl[64][65];
  const int pxb = blockIdx.x >> 2;
  const int chb = blockIdx.x & 3;
  const int b = blockIdx.y;
  const int px0 = pxb * 64;
  const int ch0 = chb * 64;
  const int tid = threadIdx.x;
  #pragma unroll
  for (int i = 0; i < 2; ++i) {
    int p = (tid >> 3) + 32 * i;
    int c8 = (tid & 7) * 8;
    size_t e = ((size_t)b * HWPX + px0 + p) * 256 + ch0 + c8;
    const float* scp = sc + b * 256 + ch0 + c8;
    const float* shp = sh + b * 256 + ch0 + c8;
    float4 s0 = ((const float4*)scp)[0], s1 = ((const float4*)scp)[1];
    float4 h0 = ((const float4*)shp)[0], h1 = ((const float4*)shp)[1];
    float scv[8] = {s0.x, s0.y, s0.z, s0.w, s1.x, s1.y, s1.z, s1.w};
    float shv[8] = {h0.x, h0.y, h0.z, h0.w, h1.x, h1.y, h1.z, h1.w};
    short8 v = *(const short8*)(T + e);
    short8 rb = *(const short8*)(xB + e);
    #pragma unroll
    for (int j = 0; j < 8; ++j) {
      float f = fmaf(bf2f((unsigned short)v[j]), scv[j], shv[j]) + bf2f((unsigned short)rb[j]);
      tl[p][c8 + j] = fmaxf(f, 0.f);
    }
  }
  __syncthreads();
  float* ob = out + (size_t)b * (HWPX * 256);
  #pragma unroll
  for (int i = 0; i < 16; ++i) {
    int c = (tid >> 6) + 4 * i;
    int p = tid & 63;
    ob[(size_t)(ch0 + c) * HWPX + px0 + p] = tl[p][c];
  }
}

// ----------------------------------------------------------------
extern "C" void kernel_launch(void* const* d_in, const int* in_sizes, int n_in,
                              void* d_out, int out_size, void* d_ws, size_t ws_size,
                              hipStream_t stream) {
  const float* pred_box   = (const float*)d_in[0];
  const float* pred_score = (const float*)d_in[1];
  const float* W1 = (const float*)d_in[2];
  const float* b1 = (const float*)d_in[3];
  const float* W2 = (const float*)d_in[4];
  const float* b2 = (const float*)d_in[5];
  const float* W3 = (const float*)d_in[6];
  const float* b3 = (const float*)d_in[7];
  const float* conv_w = (const float*)d_in[8];
  const float* gamma  = (const float*)d_in[9];
  const float* beta   = (const float*)d_in[10];
  float* out = (float*)d_out;

  char* wsb = (char*)d_ws;
  float* objf = (float*)(wsb + 0);                                      // 128 KB
  int*   bnds = (int*)(wsb + 0x40000);
  float* sc   = (float*)(wsb + 0x42000);                                // 4 KB
  float* sh   = (float*)(wsb + 0x44000);                                // 4 KB
  float* part = (float*)(wsb + 0x100000);                               // 4 MB
  unsigned short* zbuf = (unsigned short*)(wsb + 0x500000);             // 4 KB zeros
  unsigned short* wtAll = (unsigned short*)(wsb + 0x600000);            // 6.75 MB
  unsigned short* xB = (unsigned short*)(wsb + (size_t)16 * 1024 * 1024);   // 134 MB
  unsigned short* yB = (unsigned short*)(wsb + (size_t)160 * 1024 * 1024);  // 134 MB
  unsigned short* T  = (unsigned short*)(wsb + (size_t)304 * 1024 * 1024);  // 134 MB

  hipMemsetAsync(zbuf, 0, 4096, stream);
  mlp_kernel<<<128, 256, 0, stream>>>(pred_box, pred_score, W1, b1, W2, b2, W3, b3, objf);
  bounds_kernel<<<1, 128, 0, stream>>>(pred_box, bnds);
  wt_kernel<<<13824, 256, 0, stream>>>(conv_w, wtAll);
  raster_nhwc<<<dim3(256, 4), 256, 0, stream>>>(bnds, objf, xB);

  for (int k = 0; k < 3; ++k) {
    const unsigned short* wk0 = wtAll + (size_t)(k * 2 + 0) * 589824;
    const unsigned short* wk1 = wtAll + (size_t)(k * 2 + 1) * 589824;
    conv_mfma<<<2048, 256, 0, stream>>>(xB, wk0, zbuf, T, part);
    stats2<<<dim3(256, 4), 256, 0, stream>>>(part, gamma + (k * 2 + 0) * 256,
                                             beta + (k * 2 + 0) * 256, sc, sh);
    bnrelu<<<4096, 256, 0, stream>>>(T, sc, sh, yB);
    conv_mfma<<<2048, 256, 0, stream>>>(yB, wk1, zbuf, T, part);
    stats2<<<dim3(256, 4), 256, 0, stream>>>(part, gamma + (k * 2 + 1) * 256,
                                             beta + (k * 2 + 1) * 256, sc, sh);
    if (k < 2)
      bnres<<<4096, 256, 0, stream>>>(T, sc, sh, xB);
    else
      bnres_tr<<<dim3(4096, 4), 256, 0, stream>>>(T, sc, sh, xB, out);
  }
}